// Round 9
// baseline (597.961 us; speedup 1.0000x reference)
//
#include <hip/hip_runtime.h>
#include <hip/hip_cooperative_groups.h>
namespace cg = cooperative_groups;

typedef __attribute__((ext_vector_type(8))) short short8;
typedef __attribute__((ext_vector_type(4))) float f32x4;

__device__ __forceinline__ float bf2f(short s) {
  return __uint_as_float(((unsigned)(unsigned short)s) << 16);
}
__device__ __forceinline__ unsigned short f2bf(float f) {
  unsigned u = __float_as_uint(f);
  unsigned rounding = 0x7fffu + ((u >> 16) & 1u);
  return (unsigned short)((u + rounding) >> 16);
}
__device__ __forceinline__ short8 cvt8(float4 a, float4 b) {
  short8 r;
  r[0]=(short)f2bf(a.x); r[1]=(short)f2bf(a.y); r[2]=(short)f2bf(a.z); r[3]=(short)f2bf(a.w);
  r[4]=(short)f2bf(b.x); r[5]=(short)f2bf(b.y); r[6]=(short)f2bf(b.z); r[7]=(short)f2bf(b.w);
  return r;
}

// ================= cooperative: hgemm + 7 span iterations ==================
__global__ __launch_bounds__(256) void gemm_chain_kernel(
    const float* __restrict__ feats, const float* __restrict__ Wd, const float* __restrict__ bd,
    const float* __restrict__ Wl, const float* __restrict__ bl,
    const float* __restrict__ Wr, const float* __restrict__ br,
    const float* __restrict__ Gl, const float* __restrict__ bgl,
    const float* __restrict__ Gr, const float* __restrict__ bgr,
    unsigned short* __restrict__ ht)
{
  cg::grid_group grid = cg::this_grid();
  __shared__ __align__(16) unsigned short As[64][72];
  __shared__ __align__(16) unsigned short Ws[64][72];
  __shared__ float Cs[64][64];
  int tid = threadIdx.x;
  int wave = tid >> 6, lane = tid & 63;
  int lr = tid >> 3;
  int c8 = (tid & 7) * 8;

  // ---- phase 0: h = feats @ Wd.T + bd (fp32 inputs, convert in staging) ----
  if (blockIdx.x < 48) {
    int p0 = (blockIdx.x % 12) * 64;
    int n0 = (blockIdx.x / 12) * 64;
    f32x4 acc[4];
    #pragma unroll
    for (int i = 0; i < 4; ++i)
      #pragma unroll
      for (int j = 0; j < 4; ++j) acc[i][j] = 0.f;
    for (int kt = 0; kt < 8; ++kt) {
      int kb = kt * 64;
      #pragma unroll
      for (int rr = 0; rr < 64; rr += 32) {
        int row = lr + rr;
        const float* fp = feats + (size_t)(p0 + row)*512 + kb + c8;
        *(short8*)(&As[row][c8]) = cvt8(*(const float4*)fp, *(const float4*)(fp + 4));
        const float* wp = Wd + (size_t)(n0 + row)*512 + kb + c8;
        *(short8*)(&Ws[row][c8]) = cvt8(*(const float4*)wp, *(const float4*)(wp + 4));
      }
      __syncthreads();
      int q8 = (lane >> 4) * 8;
      #pragma unroll
      for (int kk = 0; kk < 2; ++kk) {
        short8 b = *(const short8*)(&Ws[wave*16 + (lane & 15)][kk*32 + q8]);
        #pragma unroll
        for (int mt = 0; mt < 4; ++mt) {
          short8 a = *(const short8*)(&As[mt*16 + (lane & 15)][kk*32 + q8]);
          acc[mt] = __builtin_amdgcn_mfma_f32_16x16x32_bf16(a, b, acc[mt], 0, 0, 0);
        }
      }
      __syncthreads();
    }
    int o = n0 + wave*16 + (lane & 15);
    float bias = bd[o];
    #pragma unroll
    for (int mt = 0; mt < 4; ++mt)
      #pragma unroll
      for (int r = 0; r < 4; ++r) {
        int row = p0 + mt*16 + (lane >> 4)*4 + r;
        ht[(size_t)row*256 + o] = f2bf(acc[mt][r] + bias);
      }
  }
  __threadfence();
  grid.sync();

  // ---- phases 1..7: span iterations (Wc converted on the fly) ----
  int p0 = (blockIdx.x % 12) * 64;
  int n0 = (blockIdx.x / 12) * 16;
  int dl = tid & 15;
  int d = n0 + dl;
  float bz  = bl[d] + br[d];
  float b0  = bgl[d] + bgr[d];
  float b1  = bgl[256 + d] + bgr[256 + d];
  float b2v = bgl[512 + d] + bgr[512 + d];

  for (int sl = 1; sl <= 7; ++sl) {
    const unsigned short* htp = ht + (size_t)(sl-1)*196608;
    unsigned short* htn = ht + (size_t)sl*196608;
    int Mvalid = 768 - sl;
    f32x4 acc[4];
    #pragma unroll
    for (int i = 0; i < 4; ++i)
      #pragma unroll
      for (int j = 0; j < 4; ++j) acc[i][j] = 0.f;
    for (int kt = 0; kt < 8; ++kt) {
      int kb = kt * 64;
      int shift = kb >> 8;
      int kcol = kb & 255;
      #pragma unroll
      for (int rr = 0; rr < 64; rr += 32) {
        int row = lr + rr;
        int grow = p0 + row + shift; if (grow > 767) grow = 767;
        *(short8*)(&As[row][c8]) = *(const short8*)(htp + (size_t)grow*256 + kcol + c8);
        int seg = row >> 4;
        int orow = n0 + (row & 15);
        const float* wsrc;
        if (kt < 4) wsrc = (seg == 0) ? (Wl + (size_t)orow*256 + kb + c8)
                                      : (Gl + ((size_t)(seg-1)*256 + orow)*256 + kb + c8);
        else        wsrc = (seg == 0) ? (Wr + (size_t)orow*256 + (kb - 256) + c8)
                                      : (Gr + ((size_t)(seg-1)*256 + orow)*256 + (kb - 256) + c8);
        *(short8*)(&Ws[row][c8]) = cvt8(*(const float4*)wsrc, *(const float4*)(wsrc + 4));
      }
      __syncthreads();
      int q8 = (lane >> 4) * 8;
      #pragma unroll
      for (int kk = 0; kk < 2; ++kk) {
        short8 b = *(const short8*)(&Ws[wave*16 + (lane & 15)][kk*32 + q8]);
        #pragma unroll
        for (int mt = 0; mt < 4; ++mt) {
          short8 a = *(const short8*)(&As[mt*16 + (lane & 15)][kk*32 + q8]);
          acc[mt] = __builtin_amdgcn_mfma_f32_16x16x32_bf16(a, b, acc[mt], 0, 0, 0);
        }
      }
      __syncthreads();
    }
    #pragma unroll
    for (int mt = 0; mt < 4; ++mt)
      #pragma unroll
      for (int r = 0; r < 4; ++r)
        Cs[mt*16 + (lane >> 4)*4 + r][wave*16 + (lane & 15)] = acc[mt][r];
    __syncthreads();
    for (int pr = tid >> 4; pr < 64; pr += 16) {
      int p = p0 + pr;
      if (p < Mvalid) {
        float z  = Cs[pr][dl]      + bz;
        float g0 = Cs[pr][16 + dl] + b0;
        float g1 = Cs[pr][32 + dl] + b1;
        float g2 = Cs[pr][48 + dl] + b2v;
        float l = bf2f((short)htp[(size_t)p*256 + d]);
        float r = bf2f((short)htp[(size_t)(p+1)*256 + d]);
        float hh = 4.f / (1.f + __expf(-z)) - 2.f;
        float mg = fmaxf(g0, fmaxf(g1, g2));
        float e0 = __expf(g0 - mg), e1 = __expf(g1 - mg), e2 = __expf(g2 - mg);
        htn[(size_t)p*256 + d] = f2bf((e0*hh + e1*l + e2*r) / (e0 + e1 + e2));
      }
    }
    __threadfence();
    grid.sync();
  }
}

// ================= band + chunk transfer matrices, fused ===================
// One block per chunk (48). Band rows and Xn live in LDS only.
#define HPAD 264
__global__ __launch_bounds__(256) void bandchunk_kernel(
    const unsigned short* __restrict__ htall, const float* __restrict__ Wt,
    const float* __restrict__ bt, const float* __restrict__ trans,
    float* __restrict__ Bband, float* __restrict__ mug,
    float* __restrict__ T, float* __restrict__ Tmax)
{
  __shared__ __align__(16) unsigned short hrow[8][16][HPAD]; // 67.6 KB
  __shared__ __align__(16) float Wts[3072];                  // 12 KB
  __shared__ float Bls[16][100];
  __shared__ float Xls[16][100];
  __shared__ float muls[16], sfs[16];
  __shared__ float redmax[4];
  int c = blockIdx.x;
  int a = c * 16;
  int tid = threadIdx.x;

  // stage 8 sl-levels x 16 rows of ht (rows a-sl+j), zeros for p<0
  for (int q = tid; q < 4096; q += 256) {
    int sl = q >> 9;
    int rem = q & 511;
    int j = rem >> 5;
    int cc = (rem & 31) * 8;
    int p = a - sl + j;
    short8 v;
    if (p >= 0) v = *(const short8*)(htall + ((size_t)sl*768 + p)*256 + cc);
    else { for (int x = 0; x < 8; ++x) v[x] = 0; }
    *(short8*)(&hrow[sl][j][cc]) = v;
  }
  for (int q = tid; q < 3072; q += 256) Wts[q] = Wt[q];
  __syncthreads();

  // band dots: 16 i x 96 cols
  #pragma unroll
  for (int rep = 0; rep < 6; ++rep) {
    int idx = rep * 256 + tid;
    int j = idx / 96, col = idx - j * 96;
    int t = col >> 3, k = col & 7, sl = 7 - k;
    int p = a - sl + j;
    float res = -1e30f;
    if (p >= 0) {
      float acc = 0.f;
      const unsigned short* hr = &hrow[sl][j][0];
      const float* wr = &Wts[t * 256];
      for (int dch = 0; dch < 256; dch += 8) {
        short8 hv = *(const short8*)(hr + dch);
        float4 wa = *(const float4*)(wr + dch);
        float4 wb = *(const float4*)(wr + dch + 4);
        acc += wa.x*bf2f(hv[0]) + wa.y*bf2f(hv[1]) + wa.z*bf2f(hv[2]) + wa.w*bf2f(hv[3])
             + wb.x*bf2f(hv[4]) + wb.y*bf2f(hv[5]) + wb.z*bf2f(hv[6]) + wb.w*bf2f(hv[7]);
      }
      res = acc + bt[t];
    }
    Bls[j][col] = res;
  }
  __syncthreads();
  if (tid < 16) {
    float m = -1e30f;
    for (int col = 0; col < 96; ++col) m = fmaxf(m, Bls[tid][col]);
    muls[tid] = m;
    sfs[tid] = __expf(-m);
    mug[a + 1 + tid] = m;
  }
  __syncthreads();
  #pragma unroll
  for (int rep = 0; rep < 6; ++rep) {
    int idx = rep * 256 + tid;
    int j = idx / 96, col = idx - j * 96;
    float b = Bls[j][col];
    Bband[(size_t)(a + 1 + j) * 96 + col] = b;
    Xls[j][col] = __expf(b - muls[j]);
  }
  __syncthreads();

  // basis-column propagation (5 passes x 20 groups of 12 lanes)
  int wv = tid >> 6, lane = tid & 63;
  int g = lane / 12;
  int t = lane - g * 12;
  float Etc[12];
  #pragma unroll
  for (int j = 0; j < 12; ++j) Etc[j] = __expf(trans[j*12 + t]);
  int gb = (g * 12) * 4;
  float tmax = 0.f;
  for (int pass = 0; pass < 5; ++pass) {
    int cidx = pass * 20 + wv * 5 + g;
    bool act = (g < 5) && (cidx < 96);
    int cc2 = act ? cidx : 95;
    int s = cc2 / 12, tau = cc2 - s * 12;
    float NA[8], V[8];
    #pragma unroll
    for (int j = 0; j < 8; ++j) { NA[j] = 0.f; V[j] = 0.f; }
    #pragma unroll
    for (int j = 0; j < 8; ++j) if (j == s) {
      NA[j] = (t == tau) ? 1.f : 0.f;
      V[j]  = Etc[tau];
    }
    #pragma unroll
    for (int m = 1; m <= 16; ++m) {
      int jj = m - 1;
      const float* xr = &Xls[jj][t * 8];
      float4 x0 = *(const float4*)xr;
      float4 x1 = *(const float4*)(xr + 4);
      float sf = sfs[jj];
      float na = x0.x*V[0] + x0.y*V[1] + x0.z*V[2] + x0.w*V[3]
               + x1.x*V[4] + x1.y*V[5] + x1.z*V[6] + x1.w*V[7];
      int nai = __float_as_int(na);
      float nb[12];
      #pragma unroll
      for (int j = 0; j < 12; ++j)
        nb[j] = __int_as_float(__builtin_amdgcn_ds_bpermute(gb + j*4, nai));
      float p0 = nb[0]*Etc[0] + nb[1]*Etc[1] + nb[2]*Etc[2]  + nb[3]*Etc[3];
      float p1 = nb[4]*Etc[4] + nb[5]*Etc[5] + nb[6]*Etc[6]  + nb[7]*Etc[7];
      float p2 = nb[8]*Etc[8] + nb[9]*Etc[9] + nb[10]*Etc[10] + nb[11]*Etc[11];
      float v = (p0 + p1) + p2;
      #pragma unroll
      for (int k = 0; k < 7; ++k) { NA[k] = NA[k+1]*sf; V[k] = V[k+1]*sf; }
      NA[7] = na; V[7] = v;
    }
    if (act) {
      float* dst = T + (size_t)c * 9216 + cidx;
      #pragma unroll
      for (int j = 0; j < 8; ++j) {
        dst[(size_t)(j*12 + t) * 96] = NA[j];
        tmax = fmaxf(tmax, NA[j]);
      }
    }
  }
  #pragma unroll
  for (int off = 32; off; off >>= 1) tmax = fmaxf(tmax, __shfl_down(tmax, off));
  if (lane == 0) redmax[wv] = tmax;
  __syncthreads();
  if (tid == 0)
    Tmax[c] = fmaxf(fmaxf(fmaxf(redmax[0], redmax[1]), fmaxf(redmax[2], redmax[3])), 1e-30f);
}

// ================= tree levels: product of 4 matrices ======================
#define TP 100
__device__ __forceinline__ void mm_acc(const float* __restrict__ Bs,
                                       const float* __restrict__ Ain,
                                       int r0, int cl0, float acc[6][3])
{
  #pragma unroll
  for (int i = 0; i < 6; ++i)
    #pragma unroll
    for (int m = 0; m < 3; ++m) acc[i][m] = 0.f;
  for (int k = 0; k < 96; k += 4) {
    float4 a0 = *(const float4*)(Ain + (cl0+0)*TP + k);
    float4 a1 = *(const float4*)(Ain + (cl0+1)*TP + k);
    float4 a2 = *(const float4*)(Ain + (cl0+2)*TP + k);
    #pragma unroll
    for (int i = 0; i < 6; ++i) {
      float4 b = *(const float4*)(Bs + (r0+i)*TP + k);
      acc[i][0] += b.x*a0.x + b.y*a0.y + b.z*a0.z + b.w*a0.w;
      acc[i][1] += b.x*a1.x + b.y*a1.y + b.z*a1.z + b.w*a1.w;
      acc[i][2] += b.x*a2.x + b.y*a2.y + b.z*a2.z + b.w*a2.w;
    }
  }
}

__global__ __launch_bounds__(256) void tree1_kernel(const float* __restrict__ Tin,
    const float* __restrict__ Tmax, float* __restrict__ Tout,
    float* __restrict__ TmaxO, float* __restrict__ Cout)
{
  __shared__ float Bs[96 * TP];
  __shared__ float Rt[2][48 * TP];
  __shared__ float redm[4];
  int j = blockIdx.x >> 1, slice = blockIdx.x & 1;
  int c0 = slice * 48;
  int tid = threadIdx.x;
  const float* M0 = Tin + (size_t)(4*j    ) * 9216;
  const float* M1 = Tin + (size_t)(4*j + 1) * 9216;
  const float* M2 = Tin + (size_t)(4*j + 2) * 9216;
  const float* M3 = Tin + (size_t)(4*j + 3) * 9216;
  float m0 = Tmax[4*j], m1 = Tmax[4*j+1], m2 = Tmax[4*j+2], m3 = Tmax[4*j+3];
  float i0 = 1.f/m0, i1 = 1.f/m1, i2 = 1.f/m2, i3 = 1.f/m3;

  for (int q = tid; q < 4608; q += 256) {     // A slice, col-major, scaled
    int k = q / 48, cc = q - k*48;
    Rt[0][cc*TP + k] = M0[(size_t)k*96 + c0 + cc] * i0;
  }
  for (int q = tid; q < 9216; q += 256) {     // B = M1 row-major, scaled
    int r = q / 96, k = q - r*96;
    Bs[r*TP + k] = M1[q] * i1;
  }
  __syncthreads();
  int r0 = (tid >> 4) * 6, cl0 = (tid & 15) * 3;
  float acc[6][3];
  float4 p[9];
  #pragma unroll
  for (int q = 0; q < 9; ++q) p[q] = *(const float4*)(M2 + tid*36 + q*4);
  mm_acc(Bs, Rt[0], r0, cl0, acc);
  #pragma unroll
  for (int i = 0; i < 6; ++i)
    #pragma unroll
    for (int m = 0; m < 3; ++m) Rt[1][(cl0+m)*TP + (r0+i)] = acc[i][m];
  __syncthreads();
  #pragma unroll
  for (int q = 0; q < 9; ++q) {
    int e = tid*36 + q*4;
    int r = e / 96, k = e - r*96;
    float4 v = p[q]; v.x *= i2; v.y *= i2; v.z *= i2; v.w *= i2;
    *(float4*)&Bs[r*TP + k] = v;
  }
  #pragma unroll
  for (int q = 0; q < 9; ++q) p[q] = *(const float4*)(M3 + tid*36 + q*4);
  __syncthreads();
  mm_acc(Bs, Rt[1], r0, cl0, acc);
  #pragma unroll
  for (int i = 0; i < 6; ++i)
    #pragma unroll
    for (int m = 0; m < 3; ++m) Rt[0][(cl0+m)*TP + (r0+i)] = acc[i][m];
  __syncthreads();
  #pragma unroll
  for (int q = 0; q < 9; ++q) {
    int e = tid*36 + q*4;
    int r = e / 96, k = e - r*96;
    float4 v = p[q]; v.x *= i3; v.y *= i3; v.z *= i3; v.w *= i3;
    *(float4*)&Bs[r*TP + k] = v;
  }
  __syncthreads();
  mm_acc(Bs, Rt[0], r0, cl0, acc);
  float* op = Tout + (size_t)j * 9216;
  float mx = 0.f;
  #pragma unroll
  for (int i = 0; i < 6; ++i)
    #pragma unroll
    for (int m = 0; m < 3; ++m) {
      float v = acc[i][m];
      op[(size_t)(r0+i)*96 + c0 + cl0 + m] = v;
      mx = fmaxf(mx, v);
    }
  int wv = tid >> 6, lane = tid & 63;
  #pragma unroll
  for (int off = 32; off; off >>= 1) mx = fmaxf(mx, __shfl_down(mx, off));
  if (lane == 0) redm[wv] = mx;
  __syncthreads();
  if (tid == 0)
    TmaxO[blockIdx.x] = fmaxf(fmaxf(fmaxf(redm[0], redm[1]), fmaxf(redm[2], redm[3])), 1e-30f);
  if (slice == 0 && tid == 0)
    Cout[j] = __logf(m0) + __logf(m1) + __logf(m2) + __logf(m3);
}

__global__ __launch_bounds__(256) void tree2_kernel(const float* __restrict__ Tin,
    const float* __restrict__ TmaxI, const float* __restrict__ Cin,
    float* __restrict__ Tout, float* __restrict__ Cout)
{
  __shared__ float Bs[96 * TP];
  __shared__ float Rt[2][48 * TP];
  int j = blockIdx.x >> 1, slice = blockIdx.x & 1;
  int c0 = slice * 48;
  int tid = threadIdx.x;
  const float* M0 = Tin + (size_t)(4*j    ) * 9216;
  const float* M1 = Tin + (size_t)(4*j + 1) * 9216;
  const float* M2 = Tin + (size_t)(4*j + 2) * 9216;
  const float* M3 = Tin + (size_t)(4*j + 3) * 9216;
  float m0 = fmaxf(TmaxI[2*(4*j  )], TmaxI[2*(4*j  )+1]);
  float m1 = fmaxf(TmaxI[2*(4*j+1)], TmaxI[2*(4*j+1)+1]);
  float m2 = fmaxf(TmaxI[2*(4*j+2)], TmaxI[2*(4*j+2)+1]);
  float m3 = fmaxf(TmaxI[2*(4*j+3)], TmaxI[2*(4*j+3)+1]);
  float i0 = 1.f/m0, i1 = 1.f/m1, i2 = 1.f/m2, i3 = 1.f/m3;

  for (int q = tid; q < 4608; q += 256) {
    int k = q / 48, cc = q - k*48;
    Rt[0][cc*TP + k] = M0[(size_t)k*96 + c0 + cc] * i0;
  }
  for (int q = tid; q < 9216; q += 256) {
    int r = q / 96, k = q - r*96;
    Bs[r*TP + k] = M1[q] * i1;
  }
  __syncthreads();
  int r0 = (tid >> 4) * 6, cl0 = (tid & 15) * 3;
  float acc[6][3];
  float4 p[9];
  #pragma unroll
  for (int q = 0; q < 9; ++q) p[q] = *(const float4*)(M2 + tid*36 + q*4);
  mm_acc(Bs, Rt[0], r0, cl0, acc);
  #pragma unroll
  for (int i = 0; i < 6; ++i)
    #pragma unroll
    for (int m = 0; m < 3; ++m) Rt[1][(cl0+m)*TP + (r0+i)] = acc[i][m];
  __syncthreads();
  #pragma unroll
  for (int q = 0; q < 9; ++q) {
    int e = tid*36 + q*4;
    int r = e / 96, k = e - r*96;
    float4 v = p[q]; v.x *= i2; v.y *= i2; v.z *= i2; v.w *= i2;
    *(float4*)&Bs[r*TP + k] = v;
  }
  #pragma unroll
  for (int q = 0; q < 9; ++q) p[q] = *(const float4*)(M3 + tid*36 + q*4);
  __syncthreads();
  mm_acc(Bs, Rt[1], r0, cl0, acc);
  #pragma unroll
  for (int i = 0; i < 6; ++i)
    #pragma unroll
    for (int m = 0; m < 3; ++m) Rt[0][(cl0+m)*TP + (r0+i)] = acc[i][m];
  __syncthreads();
  #pragma unroll
  for (int q = 0; q < 9; ++q) {
    int e = tid*36 + q*4;
    int r = e / 96, k = e - r*96;
    float4 v = p[q]; v.x *= i3; v.y *= i3; v.z *= i3; v.w *= i3;
    *(float4*)&Bs[r*TP + k] = v;
  }
  __syncthreads();
  mm_acc(Bs, Rt[0], r0, cl0, acc);
  float* op = Tout + (size_t)j * 9216;
  #pragma unroll
  for (int i = 0; i < 6; ++i)
    #pragma unroll
    for (int m = 0; m < 3; ++m)
      op[(size_t)(r0+i)*96 + c0 + cl0 + m] = acc[i][m];
  if (slice == 0 && tid == 0)
    Cout[j] = Cin[4*j] + Cin[4*j+1] + Cin[4*j+2] + Cin[4*j+3]
            + __logf(m0) + __logf(m1) + __logf(m2) + __logf(m3);
}

// ================= final: 2 matvecs + column + gold + musum ================
__global__ __launch_bounds__(256, 1) void final_kernel(const float* __restrict__ Tc,
    const float* __restrict__ Cb, const float* __restrict__ Bband,
    const float* __restrict__ mug, const float* __restrict__ trans,
    const float* __restrict__ bt, const int* __restrict__ tags,
    float* __restrict__ out)
{
  __shared__ float Qs[96 * TP];
  __shared__ float v1[96], v2[96], v3[96];
  __shared__ float red[8];
  int tid = threadIdx.x;
  int wv = tid >> 6, lane = tid & 63;

  float gold = 0.f;
  if (tid < 96) {
    int a = tags[tid*4+0], b = tags[tid*4+1], cc = tags[tid*4+2], d = tags[tid*4+3];
    float v = trans[cc*12 + d];
    int sl = b - a;
    if (sl >= 0 && sl < 8) v += Bband[(size_t)(b+1)*96 + d*8 + (7 - sl)];
    else v += bt[d];
    gold = v;
  }
  float mp = 0.f;
  for (int q = tid; q < 768; q += 256) mp += mug[1 + q];
  #pragma unroll
  for (int off = 32; off; off >>= 1) {
    gold += __shfl_down(gold, off);
    mp   += __shfl_down(mp, off);
  }
  if (lane == 0) { red[wv] = gold; red[4 + wv] = mp; }
  if (tid < 96) v1[tid] = Tc[(size_t)tid*96 + 94];        // z0 = onehot(94)
  for (int q = tid; q < 9216; q += 256) {                 // stage Q = Tc1
    int r = q / 96, k = q - r*96;
    Qs[r*TP + k] = Tc[9216 + q];
  }
  __syncthreads();
  float goldt = red[0] + red[1] + red[2] + red[3];
  float musum = red[4] + red[5] + red[6] + red[7];
  if (tid < 96) {
    float a = 0.f;
    for (int k = 0; k < 96; k += 4) {
      float4 qv = *(const float4*)&Qs[tid*TP + k];
      float4 zv = *(const float4*)&v1[k];
      a += qv.x*zv.x + qv.y*zv.y + qv.z*zv.z + qv.w*zv.w;
    }
    v2[tid] = a;
  }
  __syncthreads();
  for (int q = tid; q < 9216; q += 256) {                 // stage Q = Tc2
    int r = q / 96, k = q - r*96;
    Qs[r*TP + k] = Tc[18432 + q];
  }
  __syncthreads();
  if (tid < 96) {
    float a = 0.f;
    for (int k = 0; k < 96; k += 4) {
      float4 qv = *(const float4*)&Qs[tid*TP + k];
      float4 zv = *(const float4*)&v2[k];
      a += qv.x*zv.x + qv.y*zv.y + qv.z*zv.z + qv.w*zv.w;
    }
    v3[tid] = a;
  }
  __syncthreads();
  if (tid == 0) {
    float ls = 0.f;
    #pragma unroll
    for (int t = 0; t < 11; ++t) ls += __logf(v3[84 + t]);
    out[0] = ls + 11.f * (Cb[0] + Cb[1] + Cb[2] + musum) - goldt;
  }
}

// ---------------------------------------------------------------------------
extern "C" void kernel_launch(void* const* d_in, const int* in_sizes, int n_in,
                              void* d_out, int out_size, void* d_ws, size_t ws_size,
                              hipStream_t stream)
{
  const float* feats = (const float*)d_in[0];
  const int*   tags  = (const int*)  d_in[1];
  const float* Wd    = (const float*)d_in[2];
  const float* bd    = (const float*)d_in[3];
  const float* Wl    = (const float*)d_in[4];
  const float* bl    = (const float*)d_in[5];
  const float* Wr    = (const float*)d_in[6];
  const float* br    = (const float*)d_in[7];
  const float* Gl    = (const float*)d_in[8];
  const float* bgl   = (const float*)d_in[9];
  const float* Gr    = (const float*)d_in[10];
  const float* bgr   = (const float*)d_in[11];
  const float* Wt    = (const float*)d_in[12];
  const float* bt    = (const float*)d_in[13];
  const float* trans = (const float*)d_in[14];
  float* out = (float*)d_out;

  char* ws = (char*)d_ws;
  unsigned short* ht    = (unsigned short*)(ws + 0);        // 8*768*256 bf16 = 3,145,728
  float*          Bband = (float*)(ws + 3145728);           // 769*96 f32 (rows 1..768 used)
  float*          mug   = (float*)(ws + 3441024);           // 769 f32
  float*          T     = (float*)(ws + 3444224);           // 48*9216 f32
  float*          Tb    = (float*)(ws + 5213696);           // 12*9216 f32
  float*          Tc    = (float*)(ws + 5656064);           // 3*9216 f32
  float*          Tmax  = (float*)(ws + 5766656);           // 48
  float*          Tmax1 = (float*)(ws + 5766848);           // 24
  float*          Ca    = (float*)(ws + 5766944);           // 12
  float*          Cb    = (float*)(ws + 5766992);           // 3

  void* cargs[] = {(void*)&feats, (void*)&Wd, (void*)&bd, (void*)&Wl, (void*)&bl,
                   (void*)&Wr, (void*)&br, (void*)&Gl, (void*)&bgl, (void*)&Gr,
                   (void*)&bgr, (void*)&ht};
  hipLaunchCooperativeKernel((void*)gemm_chain_kernel, dim3(192), dim3(256), cargs, 0, stream);
  bandchunk_kernel<<<48, 256, 0, stream>>>(ht, Wt, bt, trans, Bband, mug, T, Tmax);
  tree1_kernel<<<24, 256, 0, stream>>>(T, Tmax, Tb, Tmax1, Ca);
  tree2_kernel<<<6, 256, 0, stream>>>(Tb, Tmax1, Ca, Tc, Cb);
  final_kernel<<<1, 256, 0, stream>>>(Tc, Cb, Bband, mug, trans, bt, tags, out);
}

// Round 10
// 478.994 us; speedup vs baseline: 1.2484x; 1.2484x over previous
//
#include <hip/hip_runtime.h>

typedef __attribute__((ext_vector_type(8))) short short8;
typedef __attribute__((ext_vector_type(4))) float f32x4;

__device__ __forceinline__ float bf2f(short s) {
  return __uint_as_float(((unsigned)(unsigned short)s) << 16);
}
__device__ __forceinline__ unsigned short f2bf(float f) {
  unsigned u = __float_as_uint(f);
  unsigned rounding = 0x7fffu + ((u >> 16) & 1u);
  return (unsigned short)((u + rounding) >> 16);
}
__device__ __forceinline__ short8 cvt8(float4 a, float4 b) {
  short8 r;
  r[0]=(short)f2bf(a.x); r[1]=(short)f2bf(a.y); r[2]=(short)f2bf(a.z); r[3]=(short)f2bf(a.w);
  r[4]=(short)f2bf(b.x); r[5]=(short)f2bf(b.y); r[6]=(short)f2bf(b.z); r[7]=(short)f2bf(b.w);
  return r;
}

// device-memory generation barrier (agent scope). All blocks co-resident.
__device__ __forceinline__ void gridbar(int* cnt, int* gen, int nb) {
  __threadfence();
  __syncthreads();
  if (threadIdx.x == 0) {
    int g = __hip_atomic_load(gen, __ATOMIC_RELAXED, __HIP_MEMORY_SCOPE_AGENT);
    int v = __hip_atomic_fetch_add(cnt, 1, __ATOMIC_ACQ_REL, __HIP_MEMORY_SCOPE_AGENT);
    if (v == nb - 1) {
      __hip_atomic_store(cnt, 0, __ATOMIC_RELAXED, __HIP_MEMORY_SCOPE_AGENT);
      __hip_atomic_fetch_add(gen, 1, __ATOMIC_RELEASE, __HIP_MEMORY_SCOPE_AGENT);
    } else {
      while (__hip_atomic_load(gen, __ATOMIC_ACQUIRE, __HIP_MEMORY_SCOPE_AGENT) == g)
        __builtin_amdgcn_s_sleep(8);
    }
  }
  __syncthreads();
}

// ================= persistent: hgemm + 7 span iterations ===================
__global__ __launch_bounds__(256) void chain_kernel(
    const float* __restrict__ feats, const float* __restrict__ Wd, const float* __restrict__ bd,
    const float* __restrict__ Wl, const float* __restrict__ bl,
    const float* __restrict__ Wr, const float* __restrict__ br,
    const float* __restrict__ Gl, const float* __restrict__ bgl,
    const float* __restrict__ Gr, const float* __restrict__ bgr,
    unsigned short* __restrict__ ht, int* cnt, int* gen)
{
  __shared__ __align__(16) unsigned short As[64][72];
  __shared__ __align__(16) unsigned short Ws[64][72];
  __shared__ float Cs[64][64];
  int tid = threadIdx.x;
  int wave = tid >> 6, lane = tid & 63;
  int lr = tid >> 3;
  int c8 = (tid & 7) * 8;

  // ---- phase 0: h = feats @ Wd.T + bd (fp32 in, convert in staging) ----
  if (blockIdx.x < 48) {
    int p0 = (blockIdx.x % 12) * 64;
    int n0 = (blockIdx.x / 12) * 64;
    f32x4 acc[4];
    #pragma unroll
    for (int i = 0; i < 4; ++i)
      #pragma unroll
      for (int j = 0; j < 4; ++j) acc[i][j] = 0.f;
    for (int kt = 0; kt < 8; ++kt) {
      int kb = kt * 64;
      #pragma unroll
      for (int rr = 0; rr < 64; rr += 32) {
        int row = lr + rr;
        const float* fp = feats + (size_t)(p0 + row)*512 + kb + c8;
        *(short8*)(&As[row][c8]) = cvt8(*(const float4*)fp, *(const float4*)(fp + 4));
        const float* wp = Wd + (size_t)(n0 + row)*512 + kb + c8;
        *(short8*)(&Ws[row][c8]) = cvt8(*(const float4*)wp, *(const float4*)(wp + 4));
      }
      __syncthreads();
      int q8 = (lane >> 4) * 8;
      #pragma unroll
      for (int kk = 0; kk < 2; ++kk) {
        short8 b = *(const short8*)(&Ws[wave*16 + (lane & 15)][kk*32 + q8]);
        #pragma unroll
        for (int mt = 0; mt < 4; ++mt) {
          short8 a = *(const short8*)(&As[mt*16 + (lane & 15)][kk*32 + q8]);
          acc[mt] = __builtin_amdgcn_mfma_f32_16x16x32_bf16(a, b, acc[mt], 0, 0, 0);
        }
      }
      __syncthreads();
    }
    int o = n0 + wave*16 + (lane & 15);
    float bias = bd[o];
    #pragma unroll
    for (int mt = 0; mt < 4; ++mt)
      #pragma unroll
      for (int r = 0; r < 4; ++r) {
        int row = p0 + mt*16 + (lane >> 4)*4 + r;
        ht[(size_t)row*256 + o] = f2bf(acc[mt][r] + bias);
      }
  }
  gridbar(cnt, gen, 192);

  // ---- phases 1..7: span iterations (weights converted on the fly) ----
  int p0 = (blockIdx.x % 12) * 64;
  int n0 = (blockIdx.x / 12) * 16;
  int dl = tid & 15;
  int d = n0 + dl;
  float bz  = bl[d] + br[d];
  float b0  = bgl[d] + bgr[d];
  float b1  = bgl[256 + d] + bgr[256 + d];
  float b2v = bgl[512 + d] + bgr[512 + d];

  for (int sl = 1; sl <= 7; ++sl) {
    const unsigned short* htp = ht + (size_t)(sl-1)*196608;
    unsigned short* htn = ht + (size_t)sl*196608;
    int Mvalid = 768 - sl;
    f32x4 acc[4];
    #pragma unroll
    for (int i = 0; i < 4; ++i)
      #pragma unroll
      for (int j = 0; j < 4; ++j) acc[i][j] = 0.f;
    for (int kt = 0; kt < 8; ++kt) {
      int kb = kt * 64;
      int shift = kb >> 8;
      int kcol = kb & 255;
      #pragma unroll
      for (int rr = 0; rr < 64; rr += 32) {
        int row = lr + rr;
        int grow = p0 + row + shift; if (grow > 767) grow = 767;
        *(short8*)(&As[row][c8]) = *(const short8*)(htp + (size_t)grow*256 + kcol + c8);
        int seg = row >> 4;
        int orow = n0 + (row & 15);
        const float* wsrc;
        if (kt < 4) wsrc = (seg == 0) ? (Wl + (size_t)orow*256 + kb + c8)
                                      : (Gl + ((size_t)(seg-1)*256 + orow)*256 + kb + c8);
        else        wsrc = (seg == 0) ? (Wr + (size_t)orow*256 + (kb - 256) + c8)
                                      : (Gr + ((size_t)(seg-1)*256 + orow)*256 + (kb - 256) + c8);
        *(short8*)(&Ws[row][c8]) = cvt8(*(const float4*)wsrc, *(const float4*)(wsrc + 4));
      }
      __syncthreads();
      int q8 = (lane >> 4) * 8;
      #pragma unroll
      for (int kk = 0; kk < 2; ++kk) {
        short8 b = *(const short8*)(&Ws[wave*16 + (lane & 15)][kk*32 + q8]);
        #pragma unroll
        for (int mt = 0; mt < 4; ++mt) {
          short8 a = *(const short8*)(&As[mt*16 + (lane & 15)][kk*32 + q8]);
          acc[mt] = __builtin_amdgcn_mfma_f32_16x16x32_bf16(a, b, acc[mt], 0, 0, 0);
        }
      }
      __syncthreads();
    }
    #pragma unroll
    for (int mt = 0; mt < 4; ++mt)
      #pragma unroll
      for (int r = 0; r < 4; ++r)
        Cs[mt*16 + (lane >> 4)*4 + r][wave*16 + (lane & 15)] = acc[mt][r];
    __syncthreads();
    for (int pr = tid >> 4; pr < 64; pr += 16) {
      int p = p0 + pr;
      if (p < Mvalid) {
        float z  = Cs[pr][dl]      + bz;
        float g0 = Cs[pr][16 + dl] + b0;
        float g1 = Cs[pr][32 + dl] + b1;
        float g2 = Cs[pr][48 + dl] + b2v;
        float l = bf2f((short)htp[(size_t)p*256 + d]);
        float r = bf2f((short)htp[(size_t)(p+1)*256 + d]);
        float hh = 4.f / (1.f + __expf(-z)) - 2.f;
        float mg = fmaxf(g0, fmaxf(g1, g2));
        float e0 = __expf(g0 - mg), e1 = __expf(g1 - mg), e2 = __expf(g2 - mg);
        htn[(size_t)p*256 + d] = f2bf((e0*hh + e1*l + e2*r) / (e0 + e1 + e2));
      }
    }
    if (sl < 7) gridbar(cnt, gen, 192);   // last level: kernel-end sync
  }
}

// ================= tail: band+chunk, tree 48->12->3, final =================
#define TP 100
__device__ __forceinline__ void mm_acc(const float* __restrict__ Bs,
                                       const float* __restrict__ Ain,
                                       int r0, int cl0, float acc[6][3])
{
  #pragma unroll
  for (int i = 0; i < 6; ++i)
    #pragma unroll
    for (int m = 0; m < 3; ++m) acc[i][m] = 0.f;
  for (int k = 0; k < 96; k += 4) {
    float4 a0 = *(const float4*)(Ain + (cl0+0)*TP + k);
    float4 a1 = *(const float4*)(Ain + (cl0+1)*TP + k);
    float4 a2 = *(const float4*)(Ain + (cl0+2)*TP + k);
    #pragma unroll
    for (int i = 0; i < 6; ++i) {
      float4 b = *(const float4*)(Bs + (r0+i)*TP + k);
      acc[i][0] += b.x*a0.x + b.y*a0.y + b.z*a0.z + b.w*a0.w;
      acc[i][1] += b.x*a1.x + b.y*a1.y + b.z*a1.z + b.w*a1.w;
      acc[i][2] += b.x*a2.x + b.y*a2.y + b.z*a2.z + b.w*a2.w;
    }
  }
}

__global__ __launch_bounds__(256) void tail_kernel(
    const unsigned short* __restrict__ htall, const float* __restrict__ Wt,
    const float* __restrict__ bt, const float* __restrict__ trans,
    const int* __restrict__ tags,
    float* __restrict__ Bband, float* __restrict__ mug,
    float* __restrict__ T, float* __restrict__ Tb, float* __restrict__ Tc,
    float* __restrict__ Tmax, float* __restrict__ Tmax1,
    float* __restrict__ Ca, float* __restrict__ Cb,
    int* cnt, int* gen, float* __restrict__ out)
{
  __shared__ __align__(16) char smem[92832];
  int tid = threadIdx.x;
  int wv = tid >> 6, lane = tid & 63;

  // ======== phase A: band + chunk transfer matrix (all 48 blocks) ========
  {
    unsigned short* hrow = (unsigned short*)smem;           // [8][16][264]
    float* Wts  = (float*)(smem + 67584);                   // [3072]
    float* Bls  = (float*)(smem + 79872);                   // [16][100]
    float* Xls  = (float*)(smem + 86272);                   // [16][100]
    float* muls = (float*)(smem + 92672);                   // [16]
    float* sfs  = (float*)(smem + 92736);                   // [16]
    float* redmax = (float*)(smem + 92800);                 // [4]
    int c = blockIdx.x;
    int a = c * 16;

    for (int q = tid; q < 4096; q += 256) {
      int sl = q >> 9;
      int rem = q & 511;
      int j = rem >> 5;
      int cc = (rem & 31) * 8;
      int p = a - sl + j;
      short8 v;
      if (p >= 0) v = *(const short8*)(htall + ((size_t)sl*768 + p)*256 + cc);
      else { for (int x = 0; x < 8; ++x) v[x] = 0; }
      *(short8*)(hrow + ((size_t)sl*16 + j)*264 + cc) = v;
    }
    for (int q = tid; q < 3072; q += 256) Wts[q] = Wt[q];
    __syncthreads();

    #pragma unroll
    for (int rep = 0; rep < 6; ++rep) {
      int idx = rep * 256 + tid;
      int j = idx / 96, col = idx - j * 96;
      int t = col >> 3, k = col & 7, sl = 7 - k;
      int p = a - sl + j;
      float res = -1e30f;
      if (p >= 0) {
        float acc = 0.f;
        const unsigned short* hr = hrow + ((size_t)sl*16 + j)*264;
        const float* wr = Wts + t * 256;
        for (int dch = 0; dch < 256; dch += 8) {
          short8 hv = *(const short8*)(hr + dch);
          float4 wa = *(const float4*)(wr + dch);
          float4 wb = *(const float4*)(wr + dch + 4);
          acc += wa.x*bf2f(hv[0]) + wa.y*bf2f(hv[1]) + wa.z*bf2f(hv[2]) + wa.w*bf2f(hv[3])
               + wb.x*bf2f(hv[4]) + wb.y*bf2f(hv[5]) + wb.z*bf2f(hv[6]) + wb.w*bf2f(hv[7]);
        }
        res = acc + bt[t];
      }
      Bls[j*100 + col] = res;
    }
    __syncthreads();
    if (tid < 16) {
      float m = -1e30f;
      for (int col = 0; col < 96; ++col) m = fmaxf(m, Bls[tid*100 + col]);
      muls[tid] = m;
      sfs[tid] = __expf(-m);
      mug[a + 1 + tid] = m;
    }
    __syncthreads();
    #pragma unroll
    for (int rep = 0; rep < 6; ++rep) {
      int idx = rep * 256 + tid;
      int j = idx / 96, col = idx - j * 96;
      float b = Bls[j*100 + col];
      Bband[(size_t)(a + 1 + j) * 96 + col] = b;
      Xls[j*100 + col] = __expf(b - muls[j]);
    }
    __syncthreads();

    int g = lane / 12;
    int t = lane - g * 12;
    float Etc[12];
    #pragma unroll
    for (int j = 0; j < 12; ++j) Etc[j] = __expf(trans[j*12 + t]);
    int gb = (g * 12) * 4;
    float tmax = 0.f;
    for (int pass = 0; pass < 5; ++pass) {
      int cidx = pass * 20 + wv * 5 + g;
      bool act = (g < 5) && (cidx < 96);
      int cc2 = act ? cidx : 95;
      int s = cc2 / 12, tau = cc2 - s * 12;
      float NA[8], V[8];
      #pragma unroll
      for (int j = 0; j < 8; ++j) { NA[j] = 0.f; V[j] = 0.f; }
      #pragma unroll
      for (int j = 0; j < 8; ++j) if (j == s) {
        NA[j] = (t == tau) ? 1.f : 0.f;
        V[j]  = Etc[tau];
      }
      #pragma unroll
      for (int m = 1; m <= 16; ++m) {
        int jj = m - 1;
        const float* xr = Xls + jj*100 + t * 8;
        float4 x0 = *(const float4*)xr;
        float4 x1 = *(const float4*)(xr + 4);
        float sf = sfs[jj];
        float na = x0.x*V[0] + x0.y*V[1] + x0.z*V[2] + x0.w*V[3]
                 + x1.x*V[4] + x1.y*V[5] + x1.z*V[6] + x1.w*V[7];
        int nai = __float_as_int(na);
        float nb[12];
        #pragma unroll
        for (int j = 0; j < 12; ++j)
          nb[j] = __int_as_float(__builtin_amdgcn_ds_bpermute(gb + j*4, nai));
        float p0 = nb[0]*Etc[0] + nb[1]*Etc[1] + nb[2]*Etc[2]  + nb[3]*Etc[3];
        float p1 = nb[4]*Etc[4] + nb[5]*Etc[5] + nb[6]*Etc[6]  + nb[7]*Etc[7];
        float p2 = nb[8]*Etc[8] + nb[9]*Etc[9] + nb[10]*Etc[10] + nb[11]*Etc[11];
        float v = (p0 + p1) + p2;
        #pragma unroll
        for (int k = 0; k < 7; ++k) { NA[k] = NA[k+1]*sf; V[k] = V[k+1]*sf; }
        NA[7] = na; V[7] = v;
      }
      if (act) {
        float* dst = T + (size_t)c * 9216 + cidx;
        #pragma unroll
        for (int j = 0; j < 8; ++j) {
          dst[(size_t)(j*12 + t) * 96] = NA[j];
          tmax = fmaxf(tmax, NA[j]);
        }
      }
    }
    #pragma unroll
    for (int off = 32; off; off >>= 1) tmax = fmaxf(tmax, __shfl_down(tmax, off));
    if (lane == 0) redmax[wv] = tmax;
    __syncthreads();
    if (tid == 0)
      Tmax[c] = fmaxf(fmaxf(fmaxf(redmax[0], redmax[1]), fmaxf(redmax[2], redmax[3])), 1e-30f);
  }
  gridbar(cnt, gen, 48);

  // ======== phase B: tree 48 -> 12 (blocks 0..23) ========
  {
    float* Bs  = (float*)smem;                 // [96*TP]
    float* Rt0 = (float*)(smem + 38400);       // [48*TP]
    float* Rt1 = (float*)(smem + 57600);       // [48*TP]
    float* redm = (float*)(smem + 76800);      // [4]
    if (blockIdx.x < 24) {
      int j = blockIdx.x >> 1, slice = blockIdx.x & 1;
      int c0 = slice * 48;
      const float* M0 = T + (size_t)(4*j    ) * 9216;
      const float* M1 = T + (size_t)(4*j + 1) * 9216;
      const float* M2 = T + (size_t)(4*j + 2) * 9216;
      const float* M3 = T + (size_t)(4*j + 3) * 9216;
      float m0 = Tmax[4*j], m1 = Tmax[4*j+1], m2 = Tmax[4*j+2], m3 = Tmax[4*j+3];
      float i0 = 1.f/m0, i1 = 1.f/m1, i2 = 1.f/m2, i3 = 1.f/m3;
      for (int q = tid; q < 4608; q += 256) {
        int k = q / 48, cc = q - k*48;
        Rt0[cc*TP + k] = M0[(size_t)k*96 + c0 + cc] * i0;
      }
      for (int q = tid; q < 9216; q += 256) {
        int r = q / 96, k = q - r*96;
        Bs[r*TP + k] = M1[q] * i1;
      }
      __syncthreads();
      int r0 = (tid >> 4) * 6, cl0 = (tid & 15) * 3;
      float acc[6][3];
      float4 p[9];
      #pragma unroll
      for (int q = 0; q < 9; ++q) p[q] = *(const float4*)(M2 + tid*36 + q*4);
      mm_acc(Bs, Rt0, r0, cl0, acc);
      #pragma unroll
      for (int i = 0; i < 6; ++i)
        #pragma unroll
        for (int m = 0; m < 3; ++m) Rt1[(cl0+m)*TP + (r0+i)] = acc[i][m];
      __syncthreads();
      #pragma unroll
      for (int q = 0; q < 9; ++q) {
        int e = tid*36 + q*4;
        int r = e / 96, k = e - r*96;
        float4 v = p[q]; v.x *= i2; v.y *= i2; v.z *= i2; v.w *= i2;
        *(float4*)&Bs[r*TP + k] = v;
      }
      #pragma unroll
      for (int q = 0; q < 9; ++q) p[q] = *(const float4*)(M3 + tid*36 + q*4);
      __syncthreads();
      mm_acc(Bs, Rt1, r0, cl0, acc);
      #pragma unroll
      for (int i = 0; i < 6; ++i)
        #pragma unroll
        for (int m = 0; m < 3; ++m) Rt0[(cl0+m)*TP + (r0+i)] = acc[i][m];
      __syncthreads();
      #pragma unroll
      for (int q = 0; q < 9; ++q) {
        int e = tid*36 + q*4;
        int r = e / 96, k = e - r*96;
        float4 v = p[q]; v.x *= i3; v.y *= i3; v.z *= i3; v.w *= i3;
        *(float4*)&Bs[r*TP + k] = v;
      }
      __syncthreads();
      mm_acc(Bs, Rt0, r0, cl0, acc);
      float* op = Tb + (size_t)j * 9216;
      float mx = 0.f;
      #pragma unroll
      for (int i = 0; i < 6; ++i)
        #pragma unroll
        for (int m = 0; m < 3; ++m) {
          float v = acc[i][m];
          op[(size_t)(r0+i)*96 + c0 + cl0 + m] = v;
          mx = fmaxf(mx, v);
        }
      #pragma unroll
      for (int off = 32; off; off >>= 1) mx = fmaxf(mx, __shfl_down(mx, off));
      if (lane == 0) redm[wv] = mx;
      __syncthreads();
      if (tid == 0)
        Tmax1[blockIdx.x] = fmaxf(fmaxf(fmaxf(redm[0], redm[1]), fmaxf(redm[2], redm[3])), 1e-30f);
      if (slice == 0 && tid == 0)
        Ca[j] = __logf(m0) + __logf(m1) + __logf(m2) + __logf(m3);
    }
  }
  gridbar(cnt, gen, 48);

  // ======== phase C: tree 12 -> 3 (blocks 0..5) ========
  {
    float* Bs  = (float*)smem;
    float* Rt0 = (float*)(smem + 38400);
    float* Rt1 = (float*)(smem + 57600);
    if (blockIdx.x < 6) {
      int j = blockIdx.x >> 1, slice = blockIdx.x & 1;
      int c0 = slice * 48;
      const float* M0 = Tb + (size_t)(4*j    ) * 9216;
      const float* M1 = Tb + (size_t)(4*j + 1) * 9216;
      const float* M2 = Tb + (size_t)(4*j + 2) * 9216;
      const float* M3 = Tb + (size_t)(4*j + 3) * 9216;
      float m0 = fmaxf(Tmax1[2*(4*j  )], Tmax1[2*(4*j  )+1]);
      float m1 = fmaxf(Tmax1[2*(4*j+1)], Tmax1[2*(4*j+1)+1]);
      float m2 = fmaxf(Tmax1[2*(4*j+2)], Tmax1[2*(4*j+2)+1]);
      float m3 = fmaxf(Tmax1[2*(4*j+3)], Tmax1[2*(4*j+3)+1]);
      float i0 = 1.f/m0, i1 = 1.f/m1, i2 = 1.f/m2, i3 = 1.f/m3;
      for (int q = tid; q < 4608; q += 256) {
        int k = q / 48, cc = q - k*48;
        Rt0[cc*TP + k] = M0[(size_t)k*96 + c0 + cc] * i0;
      }
      for (int q = tid; q < 9216; q += 256) {
        int r = q / 96, k = q - r*96;
        Bs[r*TP + k] = M1[q] * i1;
      }
      __syncthreads();
      int r0 = (tid >> 4) * 6, cl0 = (tid & 15) * 3;
      float acc[6][3];
      float4 p[9];
      #pragma unroll
      for (int q = 0; q < 9; ++q) p[q] = *(const float4*)(M2 + tid*36 + q*4);
      mm_acc(Bs, Rt0, r0, cl0, acc);
      #pragma unroll
      for (int i = 0; i < 6; ++i)
        #pragma unroll
        for (int m = 0; m < 3; ++m) Rt1[(cl0+m)*TP + (r0+i)] = acc[i][m];
      __syncthreads();
      #pragma unroll
      for (int q = 0; q < 9; ++q) {
        int e = tid*36 + q*4;
        int r = e / 96, k = e - r*96;
        float4 v = p[q]; v.x *= i2; v.y *= i2; v.z *= i2; v.w *= i2;
        *(float4*)&Bs[r*TP + k] = v;
      }
      #pragma unroll
      for (int q = 0; q < 9; ++q) p[q] = *(const float4*)(M3 + tid*36 + q*4);
      __syncthreads();
      mm_acc(Bs, Rt1, r0, cl0, acc);
      #pragma unroll
      for (int i = 0; i < 6; ++i)
        #pragma unroll
        for (int m = 0; m < 3; ++m) Rt0[(cl0+m)*TP + (r0+i)] = acc[i][m];
      __syncthreads();
      #pragma unroll
      for (int q = 0; q < 9; ++q) {
        int e = tid*36 + q*4;
        int r = e / 96, k = e - r*96;
        float4 v = p[q]; v.x *= i3; v.y *= i3; v.z *= i3; v.w *= i3;
        *(float4*)&Bs[r*TP + k] = v;
      }
      __syncthreads();
      mm_acc(Bs, Rt0, r0, cl0, acc);
      float* op = Tc + (size_t)j * 9216;
      #pragma unroll
      for (int i = 0; i < 6; ++i)
        #pragma unroll
        for (int m = 0; m < 3; ++m)
          op[(size_t)(r0+i)*96 + c0 + cl0 + m] = acc[i][m];
      if (slice == 0 && tid == 0)
        Cb[j] = Ca[4*j] + Ca[4*j+1] + Ca[4*j+2] + Ca[4*j+3]
              + __logf(m0) + __logf(m1) + __logf(m2) + __logf(m3);
    }
  }
  gridbar(cnt, gen, 48);

  // ======== phase D: final (block 0) ========
  if (blockIdx.x == 0) {
    float* Qs = (float*)smem;                  // [96*TP]
    float* v1 = (float*)(smem + 38400);
    float* v2 = (float*)(smem + 38784);
    float* v3 = (float*)(smem + 39168);
    float* red = (float*)(smem + 39552);       // [8]
    float gold = 0.f;
    if (tid < 96) {
      int a = tags[tid*4+0], b = tags[tid*4+1], cc = tags[tid*4+2], d = tags[tid*4+3];
      float v = trans[cc*12 + d];
      int sl = b - a;
      if (sl >= 0 && sl < 8) v += Bband[(size_t)(b+1)*96 + d*8 + (7 - sl)];
      else v += bt[d];
      gold = v;
    }
    float mp = 0.f;
    for (int q = tid; q < 768; q += 256) mp += mug[1 + q];
    #pragma unroll
    for (int off = 32; off; off >>= 1) {
      gold += __shfl_down(gold, off);
      mp   += __shfl_down(mp, off);
    }
    if (lane == 0) { red[wv] = gold; red[4 + wv] = mp; }
    if (tid < 96) v1[tid] = Tc[(size_t)tid*96 + 94];     // z0 = onehot(94)
    for (int q = tid; q < 9216; q += 256) {
      int r = q / 96, k = q - r*96;
      Qs[r*TP + k] = Tc[9216 + q];
    }
    __syncthreads();
    float goldt = red[0] + red[1] + red[2] + red[3];
    float musum = red[4] + red[5] + red[6] + red[7];
    if (tid < 96) {
      float a = 0.f;
      for (int k = 0; k < 96; k += 4) {
        float4 qv = *(const float4*)&Qs[tid*TP + k];
        float4 zv = *(const float4*)&v1[k];
        a += qv.x*zv.x + qv.y*zv.y + qv.z*zv.z + qv.w*zv.w;
      }
      v2[tid] = a;
    }
    __syncthreads();
    for (int q = tid; q < 9216; q += 256) {
      int r = q / 96, k = q - r*96;
      Qs[r*TP + k] = Tc[18432 + q];
    }
    __syncthreads();
    if (tid < 96) {
      float a = 0.f;
      for (int k = 0; k < 96; k += 4) {
        float4 qv = *(const float4*)&Qs[tid*TP + k];
        float4 zv = *(const float4*)&v2[k];
        a += qv.x*zv.x + qv.y*zv.y + qv.z*zv.z + qv.w*zv.w;
      }
      v3[tid] = a;
    }
    __syncthreads();
    if (tid == 0) {
      float ls = 0.f;
      #pragma unroll
      for (int t = 0; t < 11; ++t) ls += __logf(v3[84 + t]);
      out[0] = ls + 11.f * (Cb[0] + Cb[1] + Cb[2] + musum) - goldt;
    }
  }
}

// ---------------------------------------------------------------------------
extern "C" void kernel_launch(void* const* d_in, const int* in_sizes, int n_in,
                              void* d_out, int out_size, void* d_ws, size_t ws_size,
                              hipStream_t stream)
{
  const float* feats = (const float*)d_in[0];
  const int*   tags  = (const int*)  d_in[1];
  const float* Wd    = (const float*)d_in[2];
  const float* bd    = (const float*)d_in[3];
  const float* Wl    = (const float*)d_in[4];
  const float* bl    = (const float*)d_in[5];
  const float* Wr    = (const float*)d_in[6];
  const float* br    = (const float*)d_in[7];
  const float* Gl    = (const float*)d_in[8];
  const float* bgl   = (const float*)d_in[9];
  const float* Gr    = (const float*)d_in[10];
  const float* bgr   = (const float*)d_in[11];
  const float* Wt    = (const float*)d_in[12];
  const float* bt    = (const float*)d_in[13];
  const float* trans = (const float*)d_in[14];
  float* out = (float*)d_out;

  char* ws = (char*)d_ws;
  unsigned short* ht    = (unsigned short*)(ws + 0);        // 8*768*256 bf16
  float*          Bband = (float*)(ws + 3145728);           // 769*96 f32
  float*          mug   = (float*)(ws + 3441024);           // 769 f32
  float*          T     = (float*)(ws + 3444224);           // 48*9216 f32
  float*          Tb    = (float*)(ws + 5213696);           // 12*9216 f32
  float*          Tc    = (float*)(ws + 5656064);           // 3*9216 f32
  float*          Tmax  = (float*)(ws + 5766656);           // 48
  float*          Tmax1 = (float*)(ws + 5766848);           // 24
  float*          Ca    = (float*)(ws + 5766944);           // 12
  float*          Cb    = (float*)(ws + 5766992);           // 3
  int*            bars  = (int*)  (ws + 5767040);           // 4 ints (2 barrier pairs)

  hipMemsetAsync(bars, 0, 16, stream);
  chain_kernel<<<192, 256, 0, stream>>>(feats, Wd, bd, Wl, bl, Wr, br,
                                        Gl, bgl, Gr, bgr, ht, bars, bars + 1);
  tail_kernel<<<48, 256, 0, stream>>>(ht, Wt, bt, trans, tags, Bband, mug,
                                      T, Tb, Tc, Tmax, Tmax1, Ca, Cb,
                                      bars + 2, bars + 3, out);
}

// Round 11
// 414.485 us; speedup vs baseline: 1.4427x; 1.1556x over previous
//
#include <hip/hip_runtime.h>

typedef __attribute__((ext_vector_type(8))) short short8;
typedef __attribute__((ext_vector_type(4))) float f32x4;

__device__ __forceinline__ float bf2f(short s) {
  return __uint_as_float(((unsigned)(unsigned short)s) << 16);
}
__device__ __forceinline__ unsigned short f2bf(float f) {
  unsigned u = __float_as_uint(f);
  unsigned rounding = 0x7fffu + ((u >> 16) & 1u);
  return (unsigned short)((u + rounding) >> 16);
}
__device__ __forceinline__ short8 cvt8(float4 a, float4 b) {
  short8 r;
  r[0]=(short)f2bf(a.x); r[1]=(short)f2bf(a.y); r[2]=(short)f2bf(a.z); r[3]=(short)f2bf(a.w);
  r[4]=(short)f2bf(b.x); r[5]=(short)f2bf(b.y); r[6]=(short)f2bf(b.z); r[7]=(short)f2bf(b.w);
  return r;
}

// ---------------- prep: weights fp32 -> bf16 (Wd + combined Wc) ------------
__global__ void prep_kernel(const float* __restrict__ Wd,
                            const float* __restrict__ Wl, const float* __restrict__ Wr,
                            const float* __restrict__ Gl, const float* __restrict__ Gr,
                            unsigned short* __restrict__ WdB, unsigned short* __restrict__ WcB)
{
  int idx = blockIdx.x * 256 + threadIdx.x;
  if (idx < 131072) {
    WdB[idx] = f2bf(Wd[idx]);
  } else if (idx < 655360) {
    int j = idx - 131072;            // Wc[1024][512]
    int o = j >> 9, k = j & 511;
    float v;
    if (k < 256) v = (o < 256) ? Wl[o*256 + k] : Gl[(o-256)*256 + k];
    else { int k2 = k - 256; v = (o < 256) ? Wr[o*256 + k2] : Gr[(o-256)*256 + k2]; }
    WcB[j] = f2bf(v);
  }
}

// ================= zero-sync chain: h + 7 levels per block =================
// Block owns output rows [r0, r0+8). Level-0 halo rows [r0, r0+16) suffice
// for all 7 levels (row p at level sl needs rows p,p+1 at level sl-1).
__global__ __launch_bounds__(256) void chain_kernel(
    const float* __restrict__ feats, const unsigned short* __restrict__ WdB,
    const float* __restrict__ bd, const unsigned short* __restrict__ WcB,
    const float* __restrict__ bl, const float* __restrict__ br,
    const float* __restrict__ bgl, const float* __restrict__ bgr,
    unsigned short* __restrict__ ht)
{
  __shared__ __align__(16) unsigned short Abuf[2][17][264];  // 17 rows: +1 OOB guard
  __shared__ __align__(16) float Cs[4][16][260];             // 66.5 KB (aliased as fs)
  int tid = threadIdx.x;
  int wv = tid >> 6, lane = tid & 63;
  int r0 = blockIdx.x * 8;
  int m = lane & 15;
  int q8 = (lane >> 4) * 8;

  // ---- phase 0: h rows r0..r0+15 = feats @ Wd^T + bd ----
  unsigned short* fs = (unsigned short*)&Cs[0][0][0];        // [16][528] bf16
  for (int q = tid; q < 1024; q += 256) {
    int row = q >> 6;
    int k8 = (q & 63) * 8;
    int gr = r0 + row; if (gr > 767) gr = 767;
    const float* fp = feats + (size_t)gr * 512 + k8;
    *(short8*)(fs + row*528 + k8) = cvt8(*(const float4*)fp, *(const float4*)(fp + 4));
  }
  __syncthreads();
  {
    f32x4 acc[4];
    #pragma unroll
    for (int i = 0; i < 4; ++i)
      #pragma unroll
      for (int j = 0; j < 4; ++j) acc[i][j] = 0.f;
    for (int kk = 0; kk < 16; ++kk) {
      int k0 = kk*32 + q8;
      short8 a = *(const short8*)(fs + m*528 + k0);
      #pragma unroll
      for (int nt = 0; nt < 4; ++nt) {
        int o = wv*64 + nt*16 + m;
        short8 b = *(const short8*)(WdB + (size_t)o*512 + k0);
        acc[nt] = __builtin_amdgcn_mfma_f32_16x16x32_bf16(a, b, acc[nt], 0, 0, 0);
      }
    }
    __syncthreads();                 // fs reads done before Cs reuse later
    #pragma unroll
    for (int nt = 0; nt < 4; ++nt) {
      int d = wv*64 + nt*16 + m;
      float bias = bd[d];
      #pragma unroll
      for (int r = 0; r < 4; ++r) {
        int rl = (lane >> 4)*4 + r;
        unsigned short v = f2bf(acc[nt][r] + bias);
        Abuf[0][rl][d] = v;
        if (rl < 8) ht[(size_t)(r0 + rl)*256 + d] = v;     // level 0, all valid
      }
    }
  }
  __syncthreads();

  // gating biases: thread tid owns dim d = tid
  int d = tid;
  float bz  = bl[d] + br[d];
  float b0  = bgl[d] + bgr[d];
  float b1  = bgl[256 + d] + bgr[256 + d];
  float b2v = bgl[512 + d] + bgr[512 + d];

  int cb = 0;
  for (int sl = 1; sl <= 7; ++sl) {
    const unsigned short (*cur)[264] = Abuf[cb];
    unsigned short (*nxt)[264] = Abuf[cb ^ 1];
    // GEMM: M=16 local rows, N=1024 (wave wv owns segment wv: z/g0/g1/g2), K=512
    f32x4 acc[16];
    #pragma unroll
    for (int i = 0; i < 16; ++i)
      #pragma unroll
      for (int j = 0; j < 4; ++j) acc[i][j] = 0.f;
    for (int kk = 0; kk < 16; ++kk) {
      int k0 = kk*32 + q8;
      int rowa = m + (k0 >> 8);      // k>=256 -> right neighbor row
      int kc = k0 & 255;
      short8 a = *(const short8*)(&cur[rowa][kc]);
      #pragma unroll
      for (int nt = 0; nt < 16; ++nt) {
        int o = wv*256 + nt*16 + m;
        short8 b = *(const short8*)(WcB + (size_t)o*512 + k0);
        acc[nt] = __builtin_amdgcn_mfma_f32_16x16x32_bf16(a, b, acc[nt], 0, 0, 0);
      }
    }
    #pragma unroll
    for (int nt = 0; nt < 16; ++nt)
      #pragma unroll
      for (int r = 0; r < 4; ++r)
        Cs[wv][(lane >> 4)*4 + r][nt*16 + m] = acc[nt][r];
    __syncthreads();
    // fused gating epilogue: rows 0..14, thread's dim d
    unsigned short* gdst = ht + (size_t)sl * 196608;
    #pragma unroll
    for (int r = 0; r < 15; ++r) {
      float z  = Cs[0][r][d] + bz;
      float g0 = Cs[1][r][d] + b0;
      float g1 = Cs[2][r][d] + b1;
      float g2 = Cs[3][r][d] + b2v;
      float l  = bf2f((short)cur[r][d]);
      float rr = bf2f((short)cur[r + 1][d]);
      float hh = 4.f / (1.f + __expf(-z)) - 2.f;
      float mg = fmaxf(g0, fmaxf(g1, g2));
      float e0 = __expf(g0 - mg), e1 = __expf(g1 - mg), e2 = __expf(g2 - mg);
      unsigned short v = f2bf((e0*hh + e1*l + e2*rr) / (e0 + e1 + e2));
      nxt[r][d] = v;
      if (r < 8 && (r0 + r) < 768 - sl) gdst[(size_t)(r0 + r)*256 + d] = v;
    }
    cb ^= 1;
    __syncthreads();
  }
}

// ================= band + chunk transfer matrices (48 blocks) ==============
#define HPAD 264
__global__ __launch_bounds__(256) void bandchunk_kernel(
    const unsigned short* __restrict__ htall, const float* __restrict__ Wt,
    const float* __restrict__ bt, const float* __restrict__ trans,
    float* __restrict__ Bband, float* __restrict__ mug,
    float* __restrict__ T, float* __restrict__ Tmax)
{
  __shared__ __align__(16) unsigned short hrow[8][16][HPAD];
  __shared__ __align__(16) float Wts[3072];
  __shared__ float Bls[16][100];
  __shared__ float Xls[16][100];
  __shared__ float muls[16], sfs[16];
  __shared__ float redmax[4];
  int c = blockIdx.x;
  int a = c * 16;
  int tid = threadIdx.x;
  int wv = tid >> 6, lane = tid & 63;

  for (int q = tid; q < 4096; q += 256) {
    int sl = q >> 9;
    int rem = q & 511;
    int j = rem >> 5;
    int cc = (rem & 31) * 8;
    int p = a - sl + j;
    short8 v;
    if (p >= 0) v = *(const short8*)(htall + ((size_t)sl*768 + p)*256 + cc);
    else { for (int x = 0; x < 8; ++x) v[x] = 0; }
    *(short8*)(&hrow[sl][j][cc]) = v;
  }
  for (int q = tid; q < 3072; q += 256) Wts[q] = Wt[q];
  __syncthreads();

  #pragma unroll
  for (int rep = 0; rep < 6; ++rep) {
    int idx = rep * 256 + tid;
    int j = idx / 96, col = idx - j * 96;
    int t = col >> 3, k = col & 7, sl = 7 - k;
    int p = a - sl + j;
    float res = -1e30f;
    if (p >= 0) {
      float acc = 0.f;
      const unsigned short* hr = &hrow[sl][j][0];
      const float* wr = &Wts[t * 256];
      for (int dch = 0; dch < 256; dch += 8) {
        short8 hv = *(const short8*)(hr + dch);
        float4 wa = *(const float4*)(wr + dch);
        float4 wb = *(const float4*)(wr + dch + 4);
        acc += wa.x*bf2f(hv[0]) + wa.y*bf2f(hv[1]) + wa.z*bf2f(hv[2]) + wa.w*bf2f(hv[3])
             + wb.x*bf2f(hv[4]) + wb.y*bf2f(hv[5]) + wb.z*bf2f(hv[6]) + wb.w*bf2f(hv[7]);
      }
      res = acc + bt[t];
    }
    Bls[j][col] = res;
  }
  __syncthreads();
  if (tid < 16) {
    float mx = -1e30f;
    for (int col = 0; col < 96; ++col) mx = fmaxf(mx, Bls[tid][col]);
    muls[tid] = mx;
    sfs[tid] = __expf(-mx);
    mug[a + 1 + tid] = mx;
  }
  __syncthreads();
  #pragma unroll
  for (int rep = 0; rep < 6; ++rep) {
    int idx = rep * 256 + tid;
    int j = idx / 96, col = idx - j * 96;
    float b = Bls[j][col];
    Bband[(size_t)(a + 1 + j) * 96 + col] = b;
    Xls[j][col] = __expf(b - muls[j]);
  }
  __syncthreads();

  int g = lane / 12;
  int t = lane - g * 12;
  float Etc[12];
  #pragma unroll
  for (int j = 0; j < 12; ++j) Etc[j] = __expf(trans[j*12 + t]);
  int gb = (g * 12) * 4;
  float tmax = 0.f;
  for (int pass = 0; pass < 5; ++pass) {
    int cidx = pass * 20 + wv * 5 + g;
    bool act = (g < 5) && (cidx < 96);
    int cc2 = act ? cidx : 95;
    int s = cc2 / 12, tau = cc2 - s * 12;
    float NA[8], V[8];
    #pragma unroll
    for (int j = 0; j < 8; ++j) { NA[j] = 0.f; V[j] = 0.f; }
    #pragma unroll
    for (int j = 0; j < 8; ++j) if (j == s) {
      NA[j] = (t == tau) ? 1.f : 0.f;
      V[j]  = Etc[tau];
    }
    #pragma unroll
    for (int mstep = 1; mstep <= 16; ++mstep) {
      int jj = mstep - 1;
      const float* xr = &Xls[jj][t * 8];
      float4 x0 = *(const float4*)xr;
      float4 x1 = *(const float4*)(xr + 4);
      float sf = sfs[jj];
      float na = x0.x*V[0] + x0.y*V[1] + x0.z*V[2] + x0.w*V[3]
               + x1.x*V[4] + x1.y*V[5] + x1.z*V[6] + x1.w*V[7];
      int nai = __float_as_int(na);
      float nb[12];
      #pragma unroll
      for (int j = 0; j < 12; ++j)
        nb[j] = __int_as_float(__builtin_amdgcn_ds_bpermute(gb + j*4, nai));
      float p0 = nb[0]*Etc[0] + nb[1]*Etc[1] + nb[2]*Etc[2]  + nb[3]*Etc[3];
      float p1 = nb[4]*Etc[4] + nb[5]*Etc[5] + nb[6]*Etc[6]  + nb[7]*Etc[7];
      float p2 = nb[8]*Etc[8] + nb[9]*Etc[9] + nb[10]*Etc[10] + nb[11]*Etc[11];
      float v = (p0 + p1) + p2;
      #pragma unroll
      for (int k = 0; k < 7; ++k) { NA[k] = NA[k+1]*sf; V[k] = V[k+1]*sf; }
      NA[7] = na; V[7] = v;
    }
    if (act) {
      float* dst = T + (size_t)c * 9216 + cidx;
      #pragma unroll
      for (int j = 0; j < 8; ++j) {
        dst[(size_t)(j*12 + t) * 96] = NA[j];
        tmax = fmaxf(tmax, NA[j]);
      }
    }
  }
  #pragma unroll
  for (int off = 32; off; off >>= 1) tmax = fmaxf(tmax, __shfl_down(tmax, off));
  if (lane == 0) redmax[wv] = tmax;
  __syncthreads();
  if (tid == 0)
    Tmax[c] = fmaxf(fmaxf(fmaxf(redmax[0], redmax[1]), fmaxf(redmax[2], redmax[3])), 1e-30f);
}

// ================= tree levels: product of 4 matrices ======================
#define TP 100
__device__ __forceinline__ void mm_acc(const float* __restrict__ Bs,
                                       const float* __restrict__ Ain,
                                       int r0, int cl0, float acc[6][3])
{
  #pragma unroll
  for (int i = 0; i < 6; ++i)
    #pragma unroll
    for (int m = 0; m < 3; ++m) acc[i][m] = 0.f;
  for (int k = 0; k < 96; k += 4) {
    float4 a0 = *(const float4*)(Ain + (cl0+0)*TP + k);
    float4 a1 = *(const float4*)(Ain + (cl0+1)*TP + k);
    float4 a2 = *(const float4*)(Ain + (cl0+2)*TP + k);
    #pragma unroll
    for (int i = 0; i < 6; ++i) {
      float4 b = *(const float4*)(Bs + (r0+i)*TP + k);
      acc[i][0] += b.x*a0.x + b.y*a0.y + b.z*a0.z + b.w*a0.w;
      acc[i][1] += b.x*a1.x + b.y*a1.y + b.z*a1.z + b.w*a1.w;
      acc[i][2] += b.x*a2.x + b.y*a2.y + b.z*a2.z + b.w*a2.w;
    }
  }
}

__global__ __launch_bounds__(256) void tree1_kernel(const float* __restrict__ Tin,
    const float* __restrict__ Tmax, float* __restrict__ Tout,
    float* __restrict__ TmaxO, float* __restrict__ Cout)
{
  __shared__ float Bs[96 * TP];
  __shared__ float Rt[2][48 * TP];
  __shared__ float redm[4];
  int j = blockIdx.x >> 1, slice = blockIdx.x & 1;
  int c0 = slice * 48;
  int tid = threadIdx.x;
  const float* M0 = Tin + (size_t)(4*j    ) * 9216;
  const float* M1 = Tin + (size_t)(4*j + 1) * 9216;
  const float* M2 = Tin + (size_t)(4*j + 2) * 9216;
  const float* M3 = Tin + (size_t)(4*j + 3) * 9216;
  float m0 = Tmax[4*j], m1 = Tmax[4*j+1], m2 = Tmax[4*j+2], m3 = Tmax[4*j+3];
  float i0 = 1.f/m0, i1 = 1.f/m1, i2 = 1.f/m2, i3 = 1.f/m3;

  for (int q = tid; q < 4608; q += 256) {
    int k = q / 48, cc = q - k*48;
    Rt[0][cc*TP + k] = M0[(size_t)k*96 + c0 + cc] * i0;
  }
  for (int q = tid; q < 9216; q += 256) {
    int r = q / 96, k = q - r*96;
    Bs[r*TP + k] = M1[q] * i1;
  }
  __syncthreads();
  int r0 = (tid >> 4) * 6, cl0 = (tid & 15) * 3;
  float acc[6][3];
  float4 p[9];
  #pragma unroll
  for (int q = 0; q < 9; ++q) p[q] = *(const float4*)(M2 + tid*36 + q*4);
  mm_acc(Bs, Rt[0], r0, cl0, acc);
  #pragma unroll
  for (int i = 0; i < 6; ++i)
    #pragma unroll
    for (int m = 0; m < 3; ++m) Rt[1][(cl0+m)*TP + (r0+i)] = acc[i][m];
  __syncthreads();
  #pragma unroll
  for (int q = 0; q < 9; ++q) {
    int e = tid*36 + q*4;
    int r = e / 96, k = e - r*96;
    float4 v = p[q]; v.x *= i2; v.y *= i2; v.z *= i2; v.w *= i2;
    *(float4*)&Bs[r*TP + k] = v;
  }
  #pragma unroll
  for (int q = 0; q < 9; ++q) p[q] = *(const float4*)(M3 + tid*36 + q*4);
  __syncthreads();
  mm_acc(Bs, Rt[1], r0, cl0, acc);
  #pragma unroll
  for (int i = 0; i < 6; ++i)
    #pragma unroll
    for (int m = 0; m < 3; ++m) Rt[0][(cl0+m)*TP + (r0+i)] = acc[i][m];
  __syncthreads();
  #pragma unroll
  for (int q = 0; q < 9; ++q) {
    int e = tid*36 + q*4;
    int r = e / 96, k = e - r*96;
    float4 v = p[q]; v.x *= i3; v.y *= i3; v.z *= i3; v.w *= i3;
    *(float4*)&Bs[r*TP + k] = v;
  }
  __syncthreads();
  mm_acc(Bs, Rt[0], r0, cl0, acc);
  float* op = Tout + (size_t)j * 9216;
  float mx = 0.f;
  #pragma unroll
  for (int i = 0; i < 6; ++i)
    #pragma unroll
    for (int m = 0; m < 3; ++m) {
      float v = acc[i][m];
      op[(size_t)(r0+i)*96 + c0 + cl0 + m] = v;
      mx = fmaxf(mx, v);
    }
  int wv = tid >> 6, lane = tid & 63;
  #pragma unroll
  for (int off = 32; off; off >>= 1) mx = fmaxf(mx, __shfl_down(mx, off));
  if (lane == 0) redm[wv] = mx;
  __syncthreads();
  if (tid == 0)
    TmaxO[blockIdx.x] = fmaxf(fmaxf(fmaxf(redm[0], redm[1]), fmaxf(redm[2], redm[3])), 1e-30f);
  if (slice == 0 && tid == 0)
    Cout[j] = __logf(m0) + __logf(m1) + __logf(m2) + __logf(m3);
}

__global__ __launch_bounds__(256) void tree2_kernel(const float* __restrict__ Tin,
    const float* __restrict__ TmaxI, const float* __restrict__ Cin,
    float* __restrict__ Tout, float* __restrict__ Cout)
{
  __shared__ float Bs[96 * TP];
  __shared__ float Rt[2][48 * TP];
  int j = blockIdx.x >> 1, slice = blockIdx.x & 1;
  int c0 = slice * 48;
  int tid = threadIdx.x;
  const float* M0 = Tin + (size_t)(4*j    ) * 9216;
  const float* M1 = Tin + (size_t)(4*j + 1) * 9216;
  const float* M2 = Tin + (size_t)(4*j + 2) * 9216;
  const float* M3 = Tin + (size_t)(4*j + 3) * 9216;
  float m0 = fmaxf(TmaxI[2*(4*j  )], TmaxI[2*(4*j  )+1]);
  float m1 = fmaxf(TmaxI[2*(4*j+1)], TmaxI[2*(4*j+1)+1]);
  float m2 = fmaxf(TmaxI[2*(4*j+2)], TmaxI[2*(4*j+2)+1]);
  float m3 = fmaxf(TmaxI[2*(4*j+3)], TmaxI[2*(4*j+3)+1]);
  float i0 = 1.f/m0, i1 = 1.f/m1, i2 = 1.f/m2, i3 = 1.f/m3;

  for (int q = tid; q < 4608; q += 256) {
    int k = q / 48, cc = q - k*48;
    Rt[0][cc*TP + k] = M0[(size_t)k*96 + c0 + cc] * i0;
  }
  for (int q = tid; q < 9216; q += 256) {
    int r = q / 96, k = q - r*96;
    Bs[r*TP + k] = M1[q] * i1;
  }
  __syncthreads();
  int r0 = (tid >> 4) * 6, cl0 = (tid & 15) * 3;
  float acc[6][3];
  float4 p[9];
  #pragma unroll
  for (int q = 0; q < 9; ++q) p[q] = *(const float4*)(M2 + tid*36 + q*4);
  mm_acc(Bs, Rt[0], r0, cl0, acc);
  #pragma unroll
  for (int i = 0; i < 6; ++i)
    #pragma unroll
    for (int m = 0; m < 3; ++m) Rt[1][(cl0+m)*TP + (r0+i)] = acc[i][m];
  __syncthreads();
  #pragma unroll
  for (int q = 0; q < 9; ++q) {
    int e = tid*36 + q*4;
    int r = e / 96, k = e - r*96;
    float4 v = p[q]; v.x *= i2; v.y *= i2; v.z *= i2; v.w *= i2;
    *(float4*)&Bs[r*TP + k] = v;
  }
  #pragma unroll
  for (int q = 0; q < 9; ++q) p[q] = *(const float4*)(M3 + tid*36 + q*4);
  __syncthreads();
  mm_acc(Bs, Rt[1], r0, cl0, acc);
  #pragma unroll
  for (int i = 0; i < 6; ++i)
    #pragma unroll
    for (int m = 0; m < 3; ++m) Rt[0][(cl0+m)*TP + (r0+i)] = acc[i][m];
  __syncthreads();
  #pragma unroll
  for (int q = 0; q < 9; ++q) {
    int e = tid*36 + q*4;
    int r = e / 96, k = e - r*96;
    float4 v = p[q]; v.x *= i3; v.y *= i3; v.z *= i3; v.w *= i3;
    *(float4*)&Bs[r*TP + k] = v;
  }
  __syncthreads();
  mm_acc(Bs, Rt[0], r0, cl0, acc);
  float* op = Tout + (size_t)j * 9216;
  #pragma unroll
  for (int i = 0; i < 6; ++i)
    #pragma unroll
    for (int m = 0; m < 3; ++m)
      op[(size_t)(r0+i)*96 + c0 + cl0 + m] = acc[i][m];
  if (slice == 0 && tid == 0)
    Cout[j] = Cin[4*j] + Cin[4*j+1] + Cin[4*j+2] + Cin[4*j+3]
            + __logf(m0) + __logf(m1) + __logf(m2) + __logf(m3);
}

// ================= final: 2 matvecs + column + gold + musum ================
__global__ __launch_bounds__(256, 1) void final_kernel(const float* __restrict__ Tc,
    const float* __restrict__ Cb, const float* __restrict__ Bband,
    const float* __restrict__ mug, const float* __restrict__ trans,
    const float* __restrict__ bt, const int* __restrict__ tags,
    float* __restrict__ out)
{
  __shared__ float Qs[96 * TP];
  __shared__ float v1[96], v2[96], v3[96];
  __shared__ float red[8];
  int tid = threadIdx.x;
  int wv = tid >> 6, lane = tid & 63;

  float gold = 0.f;
  if (tid < 96) {
    int a = tags[tid*4+0], b = tags[tid*4+1], cc = tags[tid*4+2], d = tags[tid*4+3];
    float v = trans[cc*12 + d];
    int sl = b - a;
    if (sl >= 0 && sl < 8) v += Bband[(size_t)(b+1)*96 + d*8 + (7 - sl)];
    else v += bt[d];
    gold = v;
  }
  float mp = 0.f;
  for (int q = tid; q < 768; q += 256) mp += mug[1 + q];
  #pragma unroll
  for (int off = 32; off; off >>= 1) {
    gold += __shfl_down(gold, off);
    mp   += __shfl_down(mp, off);
  }
  if (lane == 0) { red[wv] = gold; red[4 + wv] = mp; }
  if (tid < 96) v1[tid] = Tc[(size_t)tid*96 + 94];        // z0 = onehot(START)
  for (int q = tid; q < 9216; q += 256) {
    int r = q / 96, k = q - r*96;
    Qs[r*TP + k] = Tc[9216 + q];
  }
  __syncthreads();
  float goldt = red[0] + red[1] + red[2] + red[3];
  float musum = red[4] + red[5] + red[6] + red[7];
  if (tid < 96) {
    float a = 0.f;
    for (int k = 0; k < 96; k += 4) {
      float4 qv = *(const float4*)&Qs[tid*TP + k];
      float4 zv = *(const float4*)&v1[k];
      a += qv.x*zv.x + qv.y*zv.y + qv.z*zv.z + qv.w*zv.w;
    }
    v2[tid] = a;
  }
  __syncthreads();
  for (int q = tid; q < 9216; q += 256) {
    int r = q / 96, k = q - r*96;
    Qs[r*TP + k] = Tc[18432 + q];
  }
  __syncthreads();
  if (tid < 96) {
    float a = 0.f;
    for (int k = 0; k < 96; k += 4) {
      float4 qv = *(const float4*)&Qs[tid*TP + k];
      float4 zv = *(const float4*)&v2[k];
      a += qv.x*zv.x + qv.y*zv.y + qv.z*zv.z + qv.w*zv.w;
    }
    v3[tid] = a;
  }
  __syncthreads();
  if (tid == 0) {
    float ls = 0.f;
    #pragma unroll
    for (int t = 0; t < 11; ++t) ls += __logf(v3[84 + t]);
    out[0] = ls + 11.f * (Cb[0] + Cb[1] + Cb[2] + musum) - goldt;
  }
}

// ---------------------------------------------------------------------------
extern "C" void kernel_launch(void* const* d_in, const int* in_sizes, int n_in,
                              void* d_out, int out_size, void* d_ws, size_t ws_size,
                              hipStream_t stream)
{
  const float* feats = (const float*)d_in[0];
  const int*   tags  = (const int*)  d_in[1];
  const float* Wd    = (const float*)d_in[2];
  const float* bd    = (const float*)d_in[3];
  const float* Wl    = (const float*)d_in[4];
  const float* bl    = (const float*)d_in[5];
  const float* Wr    = (const float*)d_in[6];
  const float* br    = (const float*)d_in[7];
  const float* Gl    = (const float*)d_in[8];
  const float* bgl   = (const float*)d_in[9];
  const float* Gr    = (const float*)d_in[10];
  const float* bgr   = (const float*)d_in[11];
  const float* Wt    = (const float*)d_in[12];
  const float* bt    = (const float*)d_in[13];
  const float* trans = (const float*)d_in[14];
  float* out = (float*)d_out;

  char* ws = (char*)d_ws;
  unsigned short* WdB   = (unsigned short*)(ws + 0);        // 256*512 bf16
  unsigned short* WcB   = (unsigned short*)(ws + 262144);   // 1024*512 bf16
  unsigned short* ht    = (unsigned short*)(ws + 1310720);  // 8*768*256 bf16
  float*          Bband = (float*)(ws + 4456448);           // 769*96 f32
  float*          mug   = (float*)(ws + 4751744);           // 769 f32
  float*          T     = (float*)(ws + 4755456);           // 48*9216 f32
  float*          Tb    = (float*)(ws + 6524928);           // 12*9216 f32
  float*          Tc    = (float*)(ws + 6967296);           // 3*9216 f32
  float*          Tmax  = (float*)(ws + 7077888);           // 48
  float*          Tmax1 = (float*)(ws + 7078144);           // 24
  float*          Ca    = (float*)(ws + 7078272);           // 12
  float*          Cb    = (float*)(ws + 7078400);           // 3

  prep_kernel<<<2560, 256, 0, stream>>>(Wd, Wl, Wr, Gl, Gr, WdB, WcB);
  chain_kernel<<<96, 256, 0, stream>>>(feats, WdB, bd, WcB, bl, br, bgl, bgr, ht);
  bandchunk_kernel<<<48, 256, 0, stream>>>(ht, Wt, bt, trans, Bband, mug, T, Tmax);
  tree1_kernel<<<24, 256, 0, stream>>>(T, Tmax, Tb, Tmax1, Ca);
  tree2_kernel<<<6, 256, 0, stream>>>(Tb, Tmax1, Ca, Tc, Cb);
  final_kernel<<<1, 256, 0, stream>>>(Tc, Cb, Bband, mug, trans, bt, tags, out);
}

// Round 12
// 268.216 us; speedup vs baseline: 2.2294x; 1.5453x over previous
//
#include <hip/hip_runtime.h>

typedef __attribute__((ext_vector_type(8))) short short8;
typedef __attribute__((ext_vector_type(4))) float f32x4;

__device__ __forceinline__ float bf2f(short s) {
  return __uint_as_float(((unsigned)(unsigned short)s) << 16);
}
__device__ __forceinline__ unsigned short f2bf(float f) {
  unsigned u = __float_as_uint(f);
  unsigned rounding = 0x7fffu + ((u >> 16) & 1u);
  return (unsigned short)((u + rounding) >> 16);
}
__device__ __forceinline__ short8 cvt8(float4 a, float4 b) {
  short8 r;
  r[0]=(short)f2bf(a.x); r[1]=(short)f2bf(a.y); r[2]=(short)f2bf(a.z); r[3]=(short)f2bf(a.w);
  r[4]=(short)f2bf(b.x); r[5]=(short)f2bf(b.y); r[6]=(short)f2bf(b.z); r[7]=(short)f2bf(b.w);
  return r;
}

// ---------------- h = feats @ Wd.T + bd (inline fp32->bf16 staging) --------
__global__ __launch_bounds__(256) void hgemm_kernel(const float* __restrict__ feats,
                                                    const float* __restrict__ Wd,
                                                    const float* __restrict__ bd,
                                                    unsigned short* __restrict__ ht)
{
  __shared__ __align__(16) unsigned short As[64][72];
  __shared__ __align__(16) unsigned short Ws[64][72];
  int p0 = blockIdx.x * 64;
  int n0 = blockIdx.y * 64;
  int tid = threadIdx.x;
  int wave = tid >> 6, lane = tid & 63;
  int lr = tid >> 3;
  int c8 = (tid & 7) * 8;
  f32x4 acc[4];
  #pragma unroll
  for (int i = 0; i < 4; ++i)
    #pragma unroll
    for (int j = 0; j < 4; ++j) acc[i][j] = 0.f;

  for (int kt = 0; kt < 8; ++kt) {
    int kb = kt * 64;
    #pragma unroll
    for (int rr = 0; rr < 64; rr += 32) {
      int row = lr + rr;
      const float* fp = feats + (size_t)(p0 + row)*512 + kb + c8;
      *(short8*)(&As[row][c8]) = cvt8(*(const float4*)fp, *(const float4*)(fp + 4));
      const float* wp = Wd + (size_t)(n0 + row)*512 + kb + c8;
      *(short8*)(&Ws[row][c8]) = cvt8(*(const float4*)wp, *(const float4*)(wp + 4));
    }
    __syncthreads();
    int q8 = (lane >> 4) * 8;
    #pragma unroll
    for (int kk = 0; kk < 2; ++kk) {
      short8 b = *(const short8*)(&Ws[wave*16 + (lane & 15)][kk*32 + q8]);
      #pragma unroll
      for (int mt = 0; mt < 4; ++mt) {
        short8 a = *(const short8*)(&As[mt*16 + (lane & 15)][kk*32 + q8]);
        acc[mt] = __builtin_amdgcn_mfma_f32_16x16x32_bf16(a, b, acc[mt], 0, 0, 0);
      }
    }
    __syncthreads();
  }
  int o = n0 + wave*16 + (lane & 15);
  float bias = bd[o];
  #pragma unroll
  for (int mt = 0; mt < 4; ++mt)
    #pragma unroll
    for (int r = 0; r < 4; ++r) {
      int row = p0 + mt*16 + (lane >> 4)*4 + r;
      ht[(size_t)row*256 + o] = f2bf(acc[mt][r] + bias);
    }
}

// ---------------- one span iteration (N-partitioned, inline weight cvt) ----
__global__ __launch_bounds__(256) void iter_kernel(const unsigned short* __restrict__ htp,
                                                   unsigned short* __restrict__ htn,
                                                   const float* __restrict__ Wl,
                                                   const float* __restrict__ Wr,
                                                   const float* __restrict__ Gl,
                                                   const float* __restrict__ Gr,
                                                   const float* __restrict__ bl,
                                                   const float* __restrict__ br,
                                                   const float* __restrict__ bgl,
                                                   const float* __restrict__ bgr,
                                                   int Mvalid)
{
  __shared__ __align__(16) unsigned short As[64][72];
  __shared__ __align__(16) unsigned short Ws[64][72];
  __shared__ float Cs[64][64];
  int p0 = blockIdx.x * 64;
  int n0 = blockIdx.y * 16;
  int tid = threadIdx.x;
  int wave = tid >> 6, lane = tid & 63;
  int lr = tid >> 3;
  int c8 = (tid & 7) * 8;
  f32x4 acc[4];
  #pragma unroll
  for (int i = 0; i < 4; ++i)
    #pragma unroll
    for (int j = 0; j < 4; ++j) acc[i][j] = 0.f;

  for (int kt = 0; kt < 8; ++kt) {
    int kb = kt * 64;
    int shift = kb >> 8;
    int kcol = kb & 255;
    #pragma unroll
    for (int rr = 0; rr < 64; rr += 32) {
      int row = lr + rr;
      int grow = p0 + row + shift; if (grow > 767) grow = 767;
      *(short8*)(&As[row][c8]) = *(const short8*)(htp + (size_t)grow*256 + kcol + c8);
      int seg = row >> 4;
      int orow = n0 + (row & 15);
      const float* wsrc;
      if (kt < 4) wsrc = (seg == 0) ? (Wl + (size_t)orow*256 + kb + c8)
                                    : (Gl + ((size_t)(seg-1)*256 + orow)*256 + kb + c8);
      else        wsrc = (seg == 0) ? (Wr + (size_t)orow*256 + (kb - 256) + c8)
                                    : (Gr + ((size_t)(seg-1)*256 + orow)*256 + (kb - 256) + c8);
      *(short8*)(&Ws[row][c8]) = cvt8(*(const float4*)wsrc, *(const float4*)(wsrc + 4));
    }
    __syncthreads();
    int q8 = (lane >> 4) * 8;
    #pragma unroll
    for (int kk = 0; kk < 2; ++kk) {
      short8 b = *(const short8*)(&Ws[wave*16 + (lane & 15)][kk*32 + q8]);
      #pragma unroll
      for (int mt = 0; mt < 4; ++mt) {
        short8 a = *(const short8*)(&As[mt*16 + (lane & 15)][kk*32 + q8]);
        acc[mt] = __builtin_amdgcn_mfma_f32_16x16x32_bf16(a, b, acc[mt], 0, 0, 0);
      }
    }
    __syncthreads();
  }
  #pragma unroll
  for (int mt = 0; mt < 4; ++mt)
    #pragma unroll
    for (int r = 0; r < 4; ++r)
      Cs[mt*16 + (lane >> 4)*4 + r][wave*16 + (lane & 15)] = acc[mt][r];
  __syncthreads();

  int dl = tid & 15;
  int d = n0 + dl;
  float bz  = bl[d] + br[d];
  float b0  = bgl[d] + bgr[d];
  float b1  = bgl[256 + d] + bgr[256 + d];
  float b2v = bgl[512 + d] + bgr[512 + d];
  for (int pr = tid >> 4; pr < 64; pr += 16) {
    int p = p0 + pr;
    if (p >= Mvalid) continue;
    float z  = Cs[pr][dl]      + bz;
    float g0 = Cs[pr][16 + dl] + b0;
    float g1 = Cs[pr][32 + dl] + b1;
    float g2 = Cs[pr][48 + dl] + b2v;
    float l = bf2f((short)htp[(size_t)p*256 + d]);
    float r = bf2f((short)htp[(size_t)(p+1)*256 + d]);
    float hh = 4.f / (1.f + __expf(-z)) - 2.f;
    float mg = fmaxf(g0, fmaxf(g1, g2));
    float e0 = __expf(g0 - mg), e1 = __expf(g1 - mg), e2 = __expf(g2 - mg);
    htn[(size_t)p*256 + d] = f2bf((e0*hh + e1*l + e2*r) / (e0 + e1 + e2));
  }
}

// ================= band + chunk transfer matrices (48 blocks) ==============
#define HPAD 264
__global__ __launch_bounds__(256) void bandchunk_kernel(
    const unsigned short* __restrict__ htall, const float* __restrict__ Wt,
    const float* __restrict__ bt, const float* __restrict__ trans,
    float* __restrict__ Bband, float* __restrict__ mug,
    float* __restrict__ T, float* __restrict__ Tmax)
{
  __shared__ __align__(16) unsigned short hrow[8][16][HPAD];
  __shared__ __align__(16) float Wts[3072];
  __shared__ float Bls[16][100];
  __shared__ float Xls[16][100];
  __shared__ float muls[16], sfs[16];
  __shared__ float redmax[4];
  int c = blockIdx.x;
  int a = c * 16;
  int tid = threadIdx.x;
  int wv = tid >> 6, lane = tid & 63;

  for (int q = tid; q < 4096; q += 256) {
    int sl = q >> 9;
    int rem = q & 511;
    int j = rem >> 5;
    int cc = (rem & 31) * 8;
    int p = a - sl + j;
    short8 v;
    if (p >= 0) v = *(const short8*)(htall + ((size_t)sl*768 + p)*256 + cc);
    else { for (int x = 0; x < 8; ++x) v[x] = 0; }
    *(short8*)(&hrow[sl][j][cc]) = v;
  }
  for (int q = tid; q < 3072; q += 256) Wts[q] = Wt[q];
  __syncthreads();

  #pragma unroll
  for (int rep = 0; rep < 6; ++rep) {
    int idx = rep * 256 + tid;
    int j = idx / 96, col = idx - j * 96;
    int t = col >> 3, k = col & 7, sl = 7 - k;
    int p = a - sl + j;
    float res = -1e30f;
    if (p >= 0) {
      float acc = 0.f;
      const unsigned short* hr = &hrow[sl][j][0];
      const float* wr = &Wts[t * 256];
      for (int dch = 0; dch < 256; dch += 8) {
        short8 hv = *(const short8*)(hr + dch);
        float4 wa = *(const float4*)(wr + dch);
        float4 wb = *(const float4*)(wr + dch + 4);
        acc += wa.x*bf2f(hv[0]) + wa.y*bf2f(hv[1]) + wa.z*bf2f(hv[2]) + wa.w*bf2f(hv[3])
             + wb.x*bf2f(hv[4]) + wb.y*bf2f(hv[5]) + wb.z*bf2f(hv[6]) + wb.w*bf2f(hv[7]);
      }
      res = acc + bt[t];
    }
    Bls[j][col] = res;
  }
  __syncthreads();
  if (tid < 16) {
    float mx = -1e30f;
    for (int col = 0; col < 96; ++col) mx = fmaxf(mx, Bls[tid][col]);
    muls[tid] = mx;
    sfs[tid] = __expf(-mx);
    mug[a + 1 + tid] = mx;
  }
  __syncthreads();
  #pragma unroll
  for (int rep = 0; rep < 6; ++rep) {
    int idx = rep * 256 + tid;
    int j = idx / 96, col = idx - j * 96;
    float b = Bls[j][col];
    Bband[(size_t)(a + 1 + j) * 96 + col] = b;
    Xls[j][col] = __expf(b - muls[j]);
  }
  __syncthreads();

  int g = lane / 12;
  int t = lane - g * 12;
  float Etc[12];
  #pragma unroll
  for (int j = 0; j < 12; ++j) Etc[j] = __expf(trans[j*12 + t]);
  int gb = (g * 12) * 4;
  float tmax = 0.f;
  for (int pass = 0; pass < 5; ++pass) {
    int cidx = pass * 20 + wv * 5 + g;
    bool act = (g < 5) && (cidx < 96);
    int cc2 = act ? cidx : 95;
    int s = cc2 / 12, tau = cc2 - s * 12;
    float NA[8], V[8];
    #pragma unroll
    for (int j = 0; j < 8; ++j) { NA[j] = 0.f; V[j] = 0.f; }
    #pragma unroll
    for (int j = 0; j < 8; ++j) if (j == s) {
      NA[j] = (t == tau) ? 1.f : 0.f;
      V[j]  = Etc[tau];
    }
    #pragma unroll
    for (int mstep = 1; mstep <= 16; ++mstep) {
      int jj = mstep - 1;
      const float* xr = &Xls[jj][t * 8];
      float4 x0 = *(const float4*)xr;
      float4 x1 = *(const float4*)(xr + 4);
      float sf = sfs[jj];
      float na = x0.x*V[0] + x0.y*V[1] + x0.z*V[2] + x0.w*V[3]
               + x1.x*V[4] + x1.y*V[5] + x1.z*V[6] + x1.w*V[7];
      int nai = __float_as_int(na);
      float nb[12];
      #pragma unroll
      for (int j = 0; j < 12; ++j)
        nb[j] = __int_as_float(__builtin_amdgcn_ds_bpermute(gb + j*4, nai));
      float p0 = nb[0]*Etc[0] + nb[1]*Etc[1] + nb[2]*Etc[2]  + nb[3]*Etc[3];
      float p1 = nb[4]*Etc[4] + nb[5]*Etc[5] + nb[6]*Etc[6]  + nb[7]*Etc[7];
      float p2 = nb[8]*Etc[8] + nb[9]*Etc[9] + nb[10]*Etc[10] + nb[11]*Etc[11];
      float v = (p0 + p1) + p2;
      #pragma unroll
      for (int k = 0; k < 7; ++k) { NA[k] = NA[k+1]*sf; V[k] = V[k+1]*sf; }
      NA[7] = na; V[7] = v;
    }
    if (act) {
      float* dst = T + (size_t)c * 9216 + cidx;
      #pragma unroll
      for (int j = 0; j < 8; ++j) {
        dst[(size_t)(j*12 + t) * 96] = NA[j];
        tmax = fmaxf(tmax, NA[j]);
      }
    }
  }
  #pragma unroll
  for (int off = 32; off; off >>= 1) tmax = fmaxf(tmax, __shfl_down(tmax, off));
  if (lane == 0) redmax[wv] = tmax;
  __syncthreads();
  if (tid == 0)
    Tmax[c] = fmaxf(fmaxf(fmaxf(redmax[0], redmax[1]), fmaxf(redmax[2], redmax[3])), 1e-30f);
}

// ================= tree levels: product of 4 matrices ======================
#define TP 100
__device__ __forceinline__ void mm_acc(const float* __restrict__ Bs,
                                       const float* __restrict__ Ain,
                                       int r0, int cl0, float acc[6][3])
{
  #pragma unroll
  for (int i = 0; i < 6; ++i)
    #pragma unroll
    for (int m = 0; m < 3; ++m) acc[i][m] = 0.f;
  for (int k = 0; k < 96; k += 4) {
    float4 a0 = *(const float4*)(Ain + (cl0+0)*TP + k);
    float4 a1 = *(const float4*)(Ain + (cl0+1)*TP + k);
    float4 a2 = *(const float4*)(Ain + (cl0+2)*TP + k);
    #pragma unroll
    for (int i = 0; i < 6; ++i) {
      float4 b = *(const float4*)(Bs + (r0+i)*TP + k);
      acc[i][0] += b.x*a0.x + b.y*a0.y + b.z*a0.z + b.w*a0.w;
      acc[i][1] += b.x*a1.x + b.y*a1.y + b.z*a1.z + b.w*a1.w;
      acc[i][2] += b.x*a2.x + b.y*a2.y + b.z*a2.z + b.w*a2.w;
    }
  }
}

__global__ __launch_bounds__(256) void tree1_kernel(const float* __restrict__ Tin,
    const float* __restrict__ Tmax, float* __restrict__ Tout,
    float* __restrict__ TmaxO, float* __restrict__ Cout)
{
  __shared__ float Bs[96 * TP];
  __shared__ float Rt[2][48 * TP];
  __shared__ float redm[4];
  int j = blockIdx.x >> 1, slice = blockIdx.x & 1;
  int c0 = slice * 48;
  int tid = threadIdx.x;
  const float* M0 = Tin + (size_t)(4*j    ) * 9216;
  const float* M1 = Tin + (size_t)(4*j + 1) * 9216;
  const float* M2 = Tin + (size_t)(4*j + 2) * 9216;
  const float* M3 = Tin + (size_t)(4*j + 3) * 9216;
  float m0 = Tmax[4*j], m1 = Tmax[4*j+1], m2 = Tmax[4*j+2], m3 = Tmax[4*j+3];
  float i0 = 1.f/m0, i1 = 1.f/m1, i2 = 1.f/m2, i3 = 1.f/m3;

  for (int q = tid; q < 4608; q += 256) {
    int k = q / 48, cc = q - k*48;
    Rt[0][cc*TP + k] = M0[(size_t)k*96 + c0 + cc] * i0;
  }
  for (int q = tid; q < 9216; q += 256) {
    int r = q / 96, k = q - r*96;
    Bs[r*TP + k] = M1[q] * i1;
  }
  __syncthreads();
  int r0 = (tid >> 4) * 6, cl0 = (tid & 15) * 3;
  float acc[6][3];
  float4 p[9];
  #pragma unroll
  for (int q = 0; q < 9; ++q) p[q] = *(const float4*)(M2 + tid*36 + q*4);
  mm_acc(Bs, Rt[0], r0, cl0, acc);
  #pragma unroll
  for (int i = 0; i < 6; ++i)
    #pragma unroll
    for (int m = 0; m < 3; ++m) Rt[1][(cl0+m)*TP + (r0+i)] = acc[i][m];
  __syncthreads();
  #pragma unroll
  for (int q = 0; q < 9; ++q) {
    int e = tid*36 + q*4;
    int r = e / 96, k = e - r*96;
    float4 v = p[q]; v.x *= i2; v.y *= i2; v.z *= i2; v.w *= i2;
    *(float4*)&Bs[r*TP + k] = v;
  }
  #pragma unroll
  for (int q = 0; q < 9; ++q) p[q] = *(const float4*)(M3 + tid*36 + q*4);
  __syncthreads();
  mm_acc(Bs, Rt[1], r0, cl0, acc);
  #pragma unroll
  for (int i = 0; i < 6; ++i)
    #pragma unroll
    for (int m = 0; m < 3; ++m) Rt[0][(cl0+m)*TP + (r0+i)] = acc[i][m];
  __syncthreads();
  #pragma unroll
  for (int q = 0; q < 9; ++q) {
    int e = tid*36 + q*4;
    int r = e / 96, k = e - r*96;
    float4 v = p[q]; v.x *= i3; v.y *= i3; v.z *= i3; v.w *= i3;
    *(float4*)&Bs[r*TP + k] = v;
  }
  __syncthreads();
  mm_acc(Bs, Rt[0], r0, cl0, acc);
  float* op = Tout + (size_t)j * 9216;
  float mx = 0.f;
  #pragma unroll
  for (int i = 0; i < 6; ++i)
    #pragma unroll
    for (int m = 0; m < 3; ++m) {
      float v = acc[i][m];
      op[(size_t)(r0+i)*96 + c0 + cl0 + m] = v;
      mx = fmaxf(mx, v);
    }
  int wv = tid >> 6, lane = tid & 63;
  #pragma unroll
  for (int off = 32; off; off >>= 1) mx = fmaxf(mx, __shfl_down(mx, off));
  if (lane == 0) redm[wv] = mx;
  __syncthreads();
  if (tid == 0)
    TmaxO[blockIdx.x] = fmaxf(fmaxf(fmaxf(redm[0], redm[1]), fmaxf(redm[2], redm[3])), 1e-30f);
  if (slice == 0 && tid == 0)
    Cout[j] = __logf(m0) + __logf(m1) + __logf(m2) + __logf(m3);
}

__global__ __launch_bounds__(256) void tree2_kernel(const float* __restrict__ Tin,
    const float* __restrict__ TmaxI, const float* __restrict__ Cin,
    float* __restrict__ Tout, float* __restrict__ Cout)
{
  __shared__ float Bs[96 * TP];
  __shared__ float Rt[2][48 * TP];
  int j = blockIdx.x >> 1, slice = blockIdx.x & 1;
  int c0 = slice * 48;
  int tid = threadIdx.x;
  const float* M0 = Tin + (size_t)(4*j    ) * 9216;
  const float* M1 = Tin + (size_t)(4*j + 1) * 9216;
  const float* M2 = Tin + (size_t)(4*j + 2) * 9216;
  const float* M3 = Tin + (size_t)(4*j + 3) * 9216;
  float m0 = fmaxf(TmaxI[2*(4*j  )], TmaxI[2*(4*j  )+1]);
  float m1 = fmaxf(TmaxI[2*(4*j+1)], TmaxI[2*(4*j+1)+1]);
  float m2 = fmaxf(TmaxI[2*(4*j+2)], TmaxI[2*(4*j+2)+1]);
  float m3 = fmaxf(TmaxI[2*(4*j+3)], TmaxI[2*(4*j+3)+1]);
  float i0 = 1.f/m0, i1 = 1.f/m1, i2 = 1.f/m2, i3 = 1.f/m3;

  for (int q = tid; q < 4608; q += 256) {
    int k = q / 48, cc = q - k*48;
    Rt[0][cc*TP + k] = M0[(size_t)k*96 + c0 + cc] * i0;
  }
  for (int q = tid; q < 9216; q += 256) {
    int r = q / 96, k = q - r*96;
    Bs[r*TP + k] = M1[q] * i1;
  }
  __syncthreads();
  int r0 = (tid >> 4) * 6, cl0 = (tid & 15) * 3;
  float acc[6][3];
  float4 p[9];
  #pragma unroll
  for (int q = 0; q < 9; ++q) p[q] = *(const float4*)(M2 + tid*36 + q*4);
  mm_acc(Bs, Rt[0], r0, cl0, acc);
  #pragma unroll
  for (int i = 0; i < 6; ++i)
    #pragma unroll
    for (int m = 0; m < 3; ++m) Rt[1][(cl0+m)*TP + (r0+i)] = acc[i][m];
  __syncthreads();
  #pragma unroll
  for (int q = 0; q < 9; ++q) {
    int e = tid*36 + q*4;
    int r = e / 96, k = e - r*96;
    float4 v = p[q]; v.x *= i2; v.y *= i2; v.z *= i2; v.w *= i2;
    *(float4*)&Bs[r*TP + k] = v;
  }
  #pragma unroll
  for (int q = 0; q < 9; ++q) p[q] = *(const float4*)(M3 + tid*36 + q*4);
  __syncthreads();
  mm_acc(Bs, Rt[1], r0, cl0, acc);
  #pragma unroll
  for (int i = 0; i < 6; ++i)
    #pragma unroll
    for (int m = 0; m < 3; ++m) Rt[0][(cl0+m)*TP + (r0+i)] = acc[i][m];
  __syncthreads();
  #pragma unroll
  for (int q = 0; q < 9; ++q) {
    int e = tid*36 + q*4;
    int r = e / 96, k = e - r*96;
    float4 v = p[q]; v.x *= i3; v.y *= i3; v.z *= i3; v.w *= i3;
    *(float4*)&Bs[r*TP + k] = v;
  }
  __syncthreads();
  mm_acc(Bs, Rt[0], r0, cl0, acc);
  float* op = Tout + (size_t)j * 9216;
  #pragma unroll
  for (int i = 0; i < 6; ++i)
    #pragma unroll
    for (int m = 0; m < 3; ++m)
      op[(size_t)(r0+i)*96 + c0 + cl0 + m] = acc[i][m];
  if (slice == 0 && tid == 0)
    Cout[j] = Cin[4*j] + Cin[4*j+1] + Cin[4*j+2] + Cin[4*j+3]
            + __logf(m0) + __logf(m1) + __logf(m2) + __logf(m3);
}

// ================= final: 2 matvecs + column + gold + musum ================
__global__ __launch_bounds__(256, 1) void final_kernel(const float* __restrict__ Tc,
    const float* __restrict__ Cb, const float* __restrict__ Bband,
    const float* __restrict__ mug, const float* __restrict__ trans,
    const float* __restrict__ bt, const int* __restrict__ tags,
    float* __restrict__ out)
{
  __shared__ float Qs[96 * TP];
  __shared__ float v1[96], v2[96], v3[96];
  __shared__ float red[8];
  int tid = threadIdx.x;
  int wv = tid >> 6, lane = tid & 63;

  float gold = 0.f;
  if (tid < 96) {
    int a = tags[tid*4+0], b = tags[tid*4+1], cc = tags[tid*4+2], d = tags[tid*4+3];
    float v = trans[cc*12 + d];
    int sl = b - a;
    if (sl >= 0 && sl < 8) v += Bband[(size_t)(b+1)*96 + d*8 + (7 - sl)];
    else v += bt[d];
    gold = v;
  }
  float mp = 0.f;
  for (int q = tid; q < 768; q += 256) mp += mug[1 + q];
  #pragma unroll
  for (int off = 32; off; off >>= 1) {
    gold += __shfl_down(gold, off);
    mp   += __shfl_down(mp, off);
  }
  if (lane == 0) { red[wv] = gold; red[4 + wv] = mp; }
  if (tid < 96) v1[tid] = Tc[(size_t)tid*96 + 94];        // z0 = onehot(START)
  for (int q = tid; q < 9216; q += 256) {
    int r = q / 96, k = q - r*96;
    Qs[r*TP + k] = Tc[9216 + q];
  }
  __syncthreads();
  float goldt = red[0] + red[1] + red[2] + red[3];
  float musum = red[4] + red[5] + red[6] + red[7];
  if (tid < 96) {
    float a = 0.f;
    for (int k = 0; k < 96; k += 4) {
      float4 qv = *(const float4*)&Qs[tid*TP + k];
      float4 zv = *(const float4*)&v1[k];
      a += qv.x*zv.x + qv.y*zv.y + qv.z*zv.z + qv.w*zv.w;
    }
    v2[tid] = a;
  }
  __syncthreads();
  for (int q = tid; q < 9216; q += 256) {
    int r = q / 96, k = q - r*96;
    Qs[r*TP + k] = Tc[18432 + q];
  }
  __syncthreads();
  if (tid < 96) {
    float a = 0.f;
    for (int k = 0; k < 96; k += 4) {
      float4 qv = *(const float4*)&Qs[tid*TP + k];
      float4 zv = *(const float4*)&v2[k];
      a += qv.x*zv.x + qv.y*zv.y + qv.z*zv.z + qv.w*zv.w;
    }
    v3[tid] = a;
  }
  __syncthreads();
  if (tid == 0) {
    float ls = 0.f;
    #pragma unroll
    for (int t = 0; t < 11; ++t) ls += __logf(v3[84 + t]);
    out[0] = ls + 11.f * (Cb[0] + Cb[1] + Cb[2] + musum) - goldt;
  }
}

// ---------------------------------------------------------------------------
extern "C" void kernel_launch(void* const* d_in, const int* in_sizes, int n_in,
                              void* d_out, int out_size, void* d_ws, size_t ws_size,
                              hipStream_t stream)
{
  const float* feats = (const float*)d_in[0];
  const int*   tags  = (const int*)  d_in[1];
  const float* Wd    = (const float*)d_in[2];
  const float* bd    = (const float*)d_in[3];
  const float* Wl    = (const float*)d_in[4];
  const float* bl    = (const float*)d_in[5];
  const float* Wr    = (const float*)d_in[6];
  const float* br    = (const float*)d_in[7];
  const float* Gl    = (const float*)d_in[8];
  const float* bgl   = (const float*)d_in[9];
  const float* Gr    = (const float*)d_in[10];
  const float* bgr   = (const float*)d_in[11];
  const float* Wt    = (const float*)d_in[12];
  const float* bt    = (const float*)d_in[13];
  const float* trans = (const float*)d_in[14];
  float* out = (float*)d_out;

  char* ws = (char*)d_ws;
  unsigned short* ht    = (unsigned short*)(ws + 0);        // 8*768*256 bf16
  float*          Bband = (float*)(ws + 3145728);           // 769*96 f32
  float*          mug   = (float*)(ws + 3441024);           // 769 f32
  float*          T     = (float*)(ws + 3444224);           // 48*9216 f32
  float*          Tb    = (float*)(ws + 5213696);           // 12*9216 f32
  float*          Tc    = (float*)(ws + 5656064);           // 3*9216 f32
  float*          Tmax  = (float*)(ws + 5766656);           // 48
  float*          Tmax1 = (float*)(ws + 5766912);           // 24
  float*          Ca    = (float*)(ws + 5767040);           // 12
  float*          Cb    = (float*)(ws + 5767168);           // 3

  hgemm_kernel<<<dim3(12, 4), 256, 0, stream>>>(feats, Wd, bd, ht);
  for (int sl = 1; sl <= 7; ++sl)
    iter_kernel<<<dim3(12, 16), 256, 0, stream>>>(ht + (size_t)(sl-1)*196608,
                                                  ht + (size_t)sl*196608,
                                                  Wl, Wr, Gl, Gr, bl, br, bgl, bgr,
                                                  768 - sl);
  bandchunk_kernel<<<48, 256, 0, stream>>>(ht, Wt, bt, trans, Bband, mug, T, Tmax);
  tree1_kernel<<<24, 256, 0, stream>>>(T, Tmax, Tb, Tmax1, Ca);
  tree2_kernel<<<6, 256, 0, stream>>>(Tb, Tmax1, Ca, Tc, Cb);
  final_kernel<<<1, 256, 0, stream>>>(Tc, Cb, Bband, mug, trans, bt, tags, out);
}

// Round 13
// 219.211 us; speedup vs baseline: 2.7278x; 1.2236x over previous
//
#include <hip/hip_runtime.h>

typedef __attribute__((ext_vector_type(8))) short short8;
typedef __attribute__((ext_vector_type(4))) float f32x4;

__device__ __forceinline__ float bf2f(short s) {
  return __uint_as_float(((unsigned)(unsigned short)s) << 16);
}
__device__ __forceinline__ unsigned short f2bf(float f) {
  unsigned u = __float_as_uint(f);
  unsigned rounding = 0x7fffu + ((u >> 16) & 1u);
  return (unsigned short)((u + rounding) >> 16);
}
__device__ __forceinline__ short8 cvt8(float4 a, float4 b) {
  short8 r;
  r[0]=(short)f2bf(a.x); r[1]=(short)f2bf(a.y); r[2]=(short)f2bf(a.z); r[3]=(short)f2bf(a.w);
  r[4]=(short)f2bf(b.x); r[5]=(short)f2bf(b.y); r[6]=(short)f2bf(b.z); r[7]=(short)f2bf(b.w);
  return r;
}

// ---------------- prep: Wc fp32->bf16 + combined biases --------------------
__global__ void prep_kernel(const float* __restrict__ Wl, const float* __restrict__ Wr,
                            const float* __restrict__ Gl, const float* __restrict__ Gr,
                            const float* __restrict__ bl, const float* __restrict__ br,
                            const float* __restrict__ bgl, const float* __restrict__ bgr,
                            unsigned short* __restrict__ WcB, float* __restrict__ bc)
{
  int idx = blockIdx.x * 256 + threadIdx.x;
  if (idx < 524288) {
    int o = idx >> 9, k = idx & 511;   // Wc[1024][512]
    float v;
    if (k < 256) v = (o < 256) ? Wl[o*256 + k] : Gl[(o-256)*256 + k];
    else { int k2 = k - 256; v = (o < 256) ? Wr[o*256 + k2] : Gr[(o-256)*256 + k2]; }
    WcB[idx] = f2bf(v);
  } else if (idx < 525312) {
    int o = idx - 524288;
    bc[o] = (o < 256) ? bl[o] + br[o] : bgl[o-256] + bgr[o-256];
  }
}

// ---------------- h = feats @ Wd.T + bd (inline fp32->bf16 staging) --------
__global__ __launch_bounds__(256) void hgemm_kernel(const float* __restrict__ feats,
                                                    const float* __restrict__ Wd,
                                                    const float* __restrict__ bd,
                                                    unsigned short* __restrict__ ht)
{
  __shared__ __align__(16) unsigned short As[64][72];
  __shared__ __align__(16) unsigned short Ws[64][72];
  int p0 = blockIdx.x * 64;
  int n0 = blockIdx.y * 64;
  int tid = threadIdx.x;
  int wave = tid >> 6, lane = tid & 63;
  int lr = tid >> 3;
  int c8 = (tid & 7) * 8;
  f32x4 acc[4];
  #pragma unroll
  for (int i = 0; i < 4; ++i)
    #pragma unroll
    for (int j = 0; j < 4; ++j) acc[i][j] = 0.f;

  for (int kt = 0; kt < 8; ++kt) {
    int kb = kt * 64;
    #pragma unroll
    for (int rr = 0; rr < 64; rr += 32) {
      int row = lr + rr;
      const float* fp = feats + (size_t)(p0 + row)*512 + kb + c8;
      *(short8*)(&As[row][c8]) = cvt8(*(const float4*)fp, *(const float4*)(fp + 4));
      const float* wp = Wd + (size_t)(n0 + row)*512 + kb + c8;
      *(short8*)(&Ws[row][c8]) = cvt8(*(const float4*)wp, *(const float4*)(wp + 4));
    }
    __syncthreads();
    int q8 = (lane >> 4) * 8;
    #pragma unroll
    for (int kk = 0; kk < 2; ++kk) {
      short8 b = *(const short8*)(&Ws[wave*16 + (lane & 15)][kk*32 + q8]);
      #pragma unroll
      for (int mt = 0; mt < 4; ++mt) {
        short8 a = *(const short8*)(&As[mt*16 + (lane & 15)][kk*32 + q8]);
        acc[mt] = __builtin_amdgcn_mfma_f32_16x16x32_bf16(a, b, acc[mt], 0, 0, 0);
      }
    }
    __syncthreads();
  }
  int o = n0 + wave*16 + (lane & 15);
  float bias = bd[o];
  #pragma unroll
  for (int mt = 0; mt < 4; ++mt)
    #pragma unroll
    for (int r = 0; r < 4; ++r) {
      int row = p0 + mt*16 + (lane >> 4)*4 + r;
      ht[(size_t)row*256 + o] = f2bf(acc[mt][r] + bias);
    }
}

// ---------------- one span iteration (bf16 weights, R8-proven) -------------
__global__ __launch_bounds__(256) void iter_kernel(const unsigned short* __restrict__ htp,
                                                   const unsigned short* __restrict__ Wc,
                                                   const float* __restrict__ bc,
                                                   unsigned short* __restrict__ htn,
                                                   int Mvalid)
{
  __shared__ __align__(16) unsigned short As[64][72];
  __shared__ __align__(16) unsigned short Ws[64][72];
  __shared__ float Cs[64][64];
  int p0 = blockIdx.x * 64;
  int n0 = blockIdx.y * 16;
  int tid = threadIdx.x;
  int wave = tid >> 6, lane = tid & 63;
  int lr = tid >> 3;
  int c8 = (tid & 7) * 8;
  f32x4 acc[4];
  #pragma unroll
  for (int i = 0; i < 4; ++i)
    #pragma unroll
    for (int j = 0; j < 4; ++j) acc[i][j] = 0.f;

  for (int kt = 0; kt < 8; ++kt) {
    int kb = kt * 64;
    int shift = kb >> 8;
    int kcol = kb & 255;
    #pragma unroll
    for (int rr = 0; rr < 64; rr += 32) {
      int row = lr + rr;
      int grow = p0 + row + shift; if (grow > 767) grow = 767;
      *(short8*)(&As[row][c8]) = *(const short8*)(htp + (size_t)grow*256 + kcol + c8);
      int o = (row >> 4)*256 + n0 + (row & 15);
      *(short8*)(&Ws[row][c8]) = *(const short8*)(Wc + (size_t)o*512 + kb + c8);
    }
    __syncthreads();
    int q8 = (lane >> 4) * 8;
    #pragma unroll
    for (int kk = 0; kk < 2; ++kk) {
      short8 b = *(const short8*)(&Ws[wave*16 + (lane & 15)][kk*32 + q8]);
      #pragma unroll
      for (int mt = 0; mt < 4; ++mt) {
        short8 a = *(const short8*)(&As[mt*16 + (lane & 15)][kk*32 + q8]);
        acc[mt] = __builtin_amdgcn_mfma_f32_16x16x32_bf16(a, b, acc[mt], 0, 0, 0);
      }
    }
    __syncthreads();
  }
  #pragma unroll
  for (int mt = 0; mt < 4; ++mt)
    #pragma unroll
    for (int r = 0; r < 4; ++r)
      Cs[mt*16 + (lane >> 4)*4 + r][wave*16 + (lane & 15)] = acc[mt][r];
  __syncthreads();

  int dl = tid & 15;
  int d = n0 + dl;
  float bz = bc[d], b0 = bc[256 + d], b1 = bc[512 + d], b2v = bc[768 + d];
  for (int pr = tid >> 4; pr < 64; pr += 16) {
    int p = p0 + pr;
    if (p >= Mvalid) continue;
    float z  = Cs[pr][dl]      + bz;
    float g0 = Cs[pr][16 + dl] + b0;
    float g1 = Cs[pr][32 + dl] + b1;
    float g2 = Cs[pr][48 + dl] + b2v;
    float l = bf2f((short)htp[(size_t)p*256 + d]);
    float r = bf2f((short)htp[(size_t)(p+1)*256 + d]);
    float hh = 4.f / (1.f + __expf(-z)) - 2.f;
    float mg = fmaxf(g0, fmaxf(g1, g2));
    float e0 = __expf(g0 - mg), e1 = __expf(g1 - mg), e2 = __expf(g2 - mg);
    float inv = 1.f / (e0 + e1 + e2);
    htn[(size_t)p*256 + d] = f2bf((e0*hh + e1*l + e2*r) * inv);
  }
}

// ---------------- band: log scores, row max, normalized exp (R8-proven) ----
__global__ __launch_bounds__(128) void band_kernel(const unsigned short* __restrict__ htall,
                                                   const float* __restrict__ Wt,
                                                   const float* __restrict__ bt,
                                                   float* __restrict__ Bband,
                                                   float* __restrict__ Xn,
                                                   float* __restrict__ mu)
{
  __shared__ __align__(16) unsigned short rows[8][264];
  __shared__ float sred[96];
  __shared__ float smu;
  int i = blockIdx.x + 1;     // 1..768
  int tid = threadIdx.x;
  for (int q = tid; q < 256; q += 128) {
    int k = q >> 5, cc = (q & 31) * 8;
    int p = i - 8 + k, sl = 7 - k;
    short8 v;
    if (p >= 0) {
      v = *(const short8*)(htall + ((size_t)sl*768 + p)*256 + cc);
    } else {
      for (int j = 0; j < 8; ++j) v[j] = 0;
    }
    *(short8*)(&rows[k][cc]) = v;
  }
  __syncthreads();
  float res = -1e30f;
  if (tid < 96) {
    int t = tid >> 3, k = tid & 7;
    int p = i - 8 + k;
    if (p >= 0) {
      float acc = 0.f;
      for (int dch = 0; dch < 256; dch += 8) {
        float4 wa = *(const float4*)(Wt + t*256 + dch);
        float4 wb = *(const float4*)(Wt + t*256 + dch + 4);
        short8 hv = *(const short8*)(&rows[k][dch]);
        acc += wa.x*bf2f(hv[0]) + wa.y*bf2f(hv[1]) + wa.z*bf2f(hv[2]) + wa.w*bf2f(hv[3])
             + wb.x*bf2f(hv[4]) + wb.y*bf2f(hv[5]) + wb.z*bf2f(hv[6]) + wb.w*bf2f(hv[7]);
      }
      res = acc + bt[t];
    }
    Bband[(size_t)i*96 + tid] = res;
    sred[tid] = res;
  }
  __syncthreads();
  if (tid < 32) {
    float m = fmaxf(sred[tid], fmaxf(sred[tid+32], sred[tid+64]));
    #pragma unroll
    for (int off = 16; off; off >>= 1) m = fmaxf(m, __shfl_down(m, off));
    if (tid == 0) { mu[i] = m; smu = m; }
  }
  __syncthreads();
  if (tid < 96) Xn[(size_t)i*96 + tid] = __expf(res - smu);
}

// ---------------- chunk transfer matrices (R8-proven, 240 blocks) ----------
__global__ __launch_bounds__(256) void chunkT_kernel(const float* __restrict__ Xn,
                                                     const float* __restrict__ mu,
                                                     const float* __restrict__ trans,
                                                     float* __restrict__ T)
{
  int chunk = blockIdx.y;
  int a = chunk * 16;
  int tid = threadIdx.x;
  int wv = tid >> 6;
  int lane = tid & 63;
  int g = lane / 12;
  int t = lane - g * 12;
  int cidx = blockIdx.x * 20 + wv * 5 + g;
  bool active = (g < 5) && (cidx < 96);
  int c = active ? cidx : 95;
  int s = c / 12, tau = c - s * 12;
  float Etc[12];
  #pragma unroll
  for (int j = 0; j < 12; ++j) Etc[j] = __expf(trans[j*12 + t]);
  float NA[8], V[8];
  #pragma unroll
  for (int j = 0; j < 8; ++j) { NA[j] = 0.f; V[j] = 0.f; }
  #pragma unroll
  for (int j = 0; j < 8; ++j) if (j == s) {
    NA[j] = (t == tau) ? 1.f : 0.f;
    V[j]  = Etc[tau];
  }
  int gb = (g * 12) * 4;
  #pragma unroll
  for (int m = 1; m <= 16; ++m) {
    const float* xr = Xn + (size_t)(a + m) * 96 + t * 8;
    float4 x0 = *(const float4*)xr;
    float4 x1 = *(const float4*)(xr + 4);
    float sf = __expf(-mu[a + m]);
    float na = x0.x*V[0] + x0.y*V[1] + x0.z*V[2] + x0.w*V[3]
             + x1.x*V[4] + x1.y*V[5] + x1.z*V[6] + x1.w*V[7];
    int nai = __float_as_int(na);
    float nb[12];
    #pragma unroll
    for (int j = 0; j < 12; ++j)
      nb[j] = __int_as_float(__builtin_amdgcn_ds_bpermute(gb + j*4, nai));
    float p0 = nb[0]*Etc[0] + nb[1]*Etc[1] + nb[2]*Etc[2]  + nb[3]*Etc[3];
    float p1 = nb[4]*Etc[4] + nb[5]*Etc[5] + nb[6]*Etc[6]  + nb[7]*Etc[7];
    float p2 = nb[8]*Etc[8] + nb[9]*Etc[9] + nb[10]*Etc[10] + nb[11]*Etc[11];
    float v = (p0 + p1) + p2;
    #pragma unroll
    for (int k = 0; k < 7; ++k) { NA[k] = NA[k+1]*sf; V[k] = V[k+1]*sf; }
    NA[7] = na; V[7] = v;
  }
  if (active) {
    float* dst = T + (size_t)chunk * 9216 + c;
    #pragma unroll
    for (int j = 0; j < 8; ++j) dst[(size_t)(j*12 + t) * 96] = NA[j];
  }
}

// ================= tree levels (radix 4, in-kernel maxes) ==================
#define TP 100
__device__ __forceinline__ void mm_acc(const float* __restrict__ Bs,
                                       const float* __restrict__ Ain,
                                       int r0, int cl0, float acc[6][3])
{
  #pragma unroll
  for (int i = 0; i < 6; ++i)
    #pragma unroll
    for (int m = 0; m < 3; ++m) acc[i][m] = 0.f;
  for (int k = 0; k < 96; k += 4) {
    float4 a0 = *(const float4*)(Ain + (cl0+0)*TP + k);
    float4 a1 = *(const float4*)(Ain + (cl0+1)*TP + k);
    float4 a2 = *(const float4*)(Ain + (cl0+2)*TP + k);
    #pragma unroll
    for (int i = 0; i < 6; ++i) {
      float4 b = *(const float4*)(Bs + (r0+i)*TP + k);
      acc[i][0] += b.x*a0.x + b.y*a0.y + b.z*a0.z + b.w*a0.w;
      acc[i][1] += b.x*a1.x + b.y*a1.y + b.z*a1.z + b.w*a1.w;
      acc[i][2] += b.x*a2.x + b.y*a2.y + b.z*a2.z + b.w*a2.w;
    }
  }
}

// block-wide max of per-thread partial (slot-indexed scratch)
__device__ __forceinline__ float blockmax(float v, float* red, int slot) {
  int wv = threadIdx.x >> 6, lane = threadIdx.x & 63;
  #pragma unroll
  for (int off = 32; off; off >>= 1) v = fmaxf(v, __shfl_down(v, off));
  if (lane == 0) red[slot*4 + wv] = v;
  __syncthreads();
  return fmaxf(fmaxf(fmaxf(red[slot*4], red[slot*4+1]),
                     fmaxf(red[slot*4+2], red[slot*4+3])), 1e-30f);
}

__device__ __forceinline__ float loadmax9(const float* M, int tid, float4* p) {
  #pragma unroll
  for (int q = 0; q < 9; ++q) p[q] = *(const float4*)(M + tid*36 + q*4);
  float mx = 0.f;
  #pragma unroll
  for (int q = 0; q < 9; ++q)
    mx = fmaxf(mx, fmaxf(fmaxf(p[q].x, p[q].y), fmaxf(p[q].z, p[q].w)));
  return mx;
}

template<int WITH_CIN>
__device__ __forceinline__ void tree_body(const float* __restrict__ Tin,
    const float* __restrict__ Cin, float* __restrict__ Tout,
    float* __restrict__ Cout, float* Bs, float* Rt0, float* Rt1, float* red)
{
  int j = blockIdx.x >> 1, slice = blockIdx.x & 1;
  int c0 = slice * 48;
  int tid = threadIdx.x;
  const float* M0 = Tin + (size_t)(4*j    ) * 9216;
  const float* M1 = Tin + (size_t)(4*j + 1) * 9216;
  const float* M2 = Tin + (size_t)(4*j + 2) * 9216;
  const float* M3 = Tin + (size_t)(4*j + 3) * 9216;
  float4 p[9];

  float fm0 = blockmax(loadmax9(M0, tid, p), red, 0);
  float i0 = 1.f / fm0;
  for (int q = tid; q < 4608; q += 256) {     // A col-major slice (from L2)
    int k = q / 48, cc = q - k*48;
    Rt0[cc*TP + k] = M0[(size_t)k*96 + c0 + cc] * i0;
  }
  float fm1 = blockmax(loadmax9(M1, tid, p), red, 1);
  float i1 = 1.f / fm1;
  #pragma unroll
  for (int q = 0; q < 9; ++q) {               // B = M1 row-major from regs
    int e = tid*36 + q*4;
    int r = e / 96, k = e - r*96;
    float4 v = p[q]; v.x *= i1; v.y *= i1; v.z *= i1; v.w *= i1;
    *(float4*)&Bs[r*TP + k] = v;
  }
  __syncthreads();
  int r0 = (tid >> 4) * 6, cl0 = (tid & 15) * 3;
  float acc[6][3];
  mm_acc(Bs, Rt0, r0, cl0, acc);
  #pragma unroll
  for (int i = 0; i < 6; ++i)
    #pragma unroll
    for (int m = 0; m < 3; ++m) Rt1[(cl0+m)*TP + (r0+i)] = acc[i][m];
  __syncthreads();

  float fm2 = blockmax(loadmax9(M2, tid, p), red, 2);
  float i2 = 1.f / fm2;
  #pragma unroll
  for (int q = 0; q < 9; ++q) {
    int e = tid*36 + q*4;
    int r = e / 96, k = e - r*96;
    float4 v = p[q]; v.x *= i2; v.y *= i2; v.z *= i2; v.w *= i2;
    *(float4*)&Bs[r*TP + k] = v;
  }
  __syncthreads();
  mm_acc(Bs, Rt1, r0, cl0, acc);
  #pragma unroll
  for (int i = 0; i < 6; ++i)
    #pragma unroll
    for (int m = 0; m < 3; ++m) Rt0[(cl0+m)*TP + (r0+i)] = acc[i][m];
  __syncthreads();

  float fm3 = blockmax(loadmax9(M3, tid, p), red, 3);
  float i3 = 1.f / fm3;
  #pragma unroll
  for (int q = 0; q < 9; ++q) {
    int e = tid*36 + q*4;
    int r = e / 96, k = e - r*96;
    float4 v = p[q]; v.x *= i3; v.y *= i3; v.z *= i3; v.w *= i3;
    *(float4*)&Bs[r*TP + k] = v;
  }
  __syncthreads();
  mm_acc(Bs, Rt0, r0, cl0, acc);
  float* op = Tout + (size_t)j * 9216;
  #pragma unroll
  for (int i = 0; i < 6; ++i)
    #pragma unroll
    for (int m = 0; m < 3; ++m)
      op[(size_t)(r0+i)*96 + c0 + cl0 + m] = acc[i][m];
  if (slice == 0 && tid == 0) {
    float base = WITH_CIN ? (Cin[4*j] + Cin[4*j+1] + Cin[4*j+2] + Cin[4*j+3]) : 0.f;
    Cout[j] = base + __logf(fm0) + __logf(fm1) + __logf(fm2) + __logf(fm3);
  }
}

__global__ __launch_bounds__(256) void tree1_kernel(const float* __restrict__ Tin,
    float* __restrict__ Tout, float* __restrict__ Cout)
{
  __shared__ float Bs[96 * TP];
  __shared__ float Rt0[48 * TP];
  __shared__ float Rt1[48 * TP];
  __shared__ float red[16];
  tree_body<0>(Tin, nullptr, Tout, Cout, Bs, Rt0, Rt1, red);
}

__global__ __launch_bounds__(256) void tree2_kernel(const float* __restrict__ Tin,
    const float* __restrict__ Cin, float* __restrict__ Tout, float* __restrict__ Cout)
{
  __shared__ float Bs[96 * TP];
  __shared__ float Rt0[48 * TP];
  __shared__ float Rt1[48 * TP];
  __shared__ float red[16];
  tree_body<1>(Tin, Cin, Tout, Cout, Bs, Rt0, Rt1, red);
}

// ================= final: 2 matvecs + column + gold + musum ================
__global__ __launch_bounds__(256, 1) void final_kernel(const float* __restrict__ Tc,
    const float* __restrict__ Cb, const float* __restrict__ Bband,
    const float* __restrict__ mug, const float* __restrict__ trans,
    const float* __restrict__ bt, const int* __restrict__ tags,
    float* __restrict__ out)
{
  __shared__ float Qs[96 * TP];
  __shared__ float v1[96], v2[96], v3[96];
  __shared__ float red[8];
  int tid = threadIdx.x;
  int wv = tid >> 6, lane = tid & 63;

  float gold = 0.f;
  if (tid < 96) {
    int a = tags[tid*4+0], b = tags[tid*4+1], cc = tags[tid*4+2], d = tags[tid*4+3];
    float v = trans[cc*12 + d];
    int sl = b - a;
    if (sl >= 0 && sl < 8) v += Bband[(size_t)(b+1)*96 + d*8 + (7 - sl)];
    else v += bt[d];
    gold = v;
  }
  float mp = 0.f;
  for (int q = tid; q < 768; q += 256) mp += mug[1 + q];
  #pragma unroll
  for (int off = 32; off; off >>= 1) {
    gold += __shfl_down(gold, off);
    mp   += __shfl_down(mp, off);
  }
  if (lane == 0) { red[wv] = gold; red[4 + wv] = mp; }
  if (tid < 96) v1[tid] = Tc[(size_t)tid*96 + 94];
  for (int q = tid; q < 9216; q += 256) {
    int r = q / 96, k = q - r*96;
    Qs[r*TP + k] = Tc[9216 + q];
  }
  __syncthreads();
  float goldt = red[0] + red[1] + red[2] + red[3];
  float musum = red[4] + red[5] + red[6] + red[7];
  if (tid < 96) {
    float a = 0.f;
    for (int k = 0; k < 96; k += 4) {
      float4 qv = *(const float4*)&Qs[tid*TP + k];
      float4 zv = *(const float4*)&v1[k];
      a += qv.x*zv.x + qv.y*zv.y + qv.z*zv.z + qv.w*zv.w;
    }
    v2[tid] = a;
  }
  __syncthreads();
  for (int q = tid; q < 9216; q += 256) {
    int r = q / 96, k = q - r*96;
    Qs[r*TP + k] = Tc[18432 + q];
  }
  __syncthreads();
  if (tid < 96) {
    float a = 0.f;
    for (int k = 0; k < 96; k += 4) {
      float4 qv = *(const float4*)&Qs[tid*TP + k];
      float4 zv = *(const float4*)&v2[k];
      a += qv.x*zv.x + qv.y*zv.y + qv.z*zv.z + qv.w*zv.w;
    }
    v3[tid] = a;
  }
  __syncthreads();
  if (tid == 0) {
    float ls = 0.f;
    #pragma unroll
    for (int t = 0; t < 11; ++t) ls += __logf(v3[84 + t]);
    out[0] = ls + 11.f * (Cb[0] + Cb[1] + Cb[2] + musum) - goldt;
  }
}

// ---------------------------------------------------------------------------
extern "C" void kernel_launch(void* const* d_in, const int* in_sizes, int n_in,
                              void* d_out, int out_size, void* d_ws, size_t ws_size,
                              hipStream_t stream)
{
  const float* feats = (const float*)d_in[0];
  const int*   tags  = (const int*)  d_in[1];
  const float* Wd    = (const float*)d_in[2];
  const float* bd    = (const float*)d_in[3];
  const float* Wl    = (const float*)d_in[4];
  const float* bl    = (const float*)d_in[5];
  const float* Wr    = (const float*)d_in[6];
  const float* br    = (const float*)d_in[7];
  const float* Gl    = (const float*)d_in[8];
  const float* bgl   = (const float*)d_in[9];
  const float* Gr    = (const float*)d_in[10];
  const float* bgr   = (const float*)d_in[11];
  const float* Wt    = (const float*)d_in[12];
  const float* bt    = (const float*)d_in[13];
  const float* trans = (const float*)d_in[14];
  float* out = (float*)d_out;

  char* ws = (char*)d_ws;
  unsigned short* WcB   = (unsigned short*)(ws + 0);        // 1024*512 bf16
  float*          bc    = (float*)(ws + 1048576);           // 1024 f32
  unsigned short* ht    = (unsigned short*)(ws + 1052672);  // 8*768*256 bf16
  float*          Bband = (float*)(ws + 4198400);           // 769*96 f32
  float*          Xn    = (float*)(ws + 4493696);           // 769*96 f32
  float*          mug   = (float*)(ws + 4788992);           // 769 f32
  float*          T     = (float*)(ws + 4792320);           // 48*9216 f32
  float*          Tb    = (float*)(ws + 6561792);           // 12*9216 f32
  float*          Tc    = (float*)(ws + 7004160);           // 3*9216 f32
  float*          Ca    = (float*)(ws + 7114752);           // 12
  float*          Cb    = (float*)(ws + 7114816);           // 3

  prep_kernel<<<2052, 256, 0, stream>>>(Wl, Wr, Gl, Gr, bl, br, bgl, bgr, WcB, bc);
  hgemm_kernel<<<dim3(12, 4), 256, 0, stream>>>(feats, Wd, bd, ht);
  for (int sl = 1; sl <= 7; ++sl)
    iter_kernel<<<dim3(12, 16), 256, 0, stream>>>(ht + (size_t)(sl-1)*196608, WcB, bc,
                                                  ht + (size_t)sl*196608, 768 - sl);
  band_kernel<<<768, 128, 0, stream>>>(ht, Wt, bt, Bband, Xn, mug);
  chunkT_kernel<<<dim3(5, 48), 256, 0, stream>>>(Xn, mug, trans, T);
  tree1_kernel<<<24, 256, 0, stream>>>(T, Tb, Ca);
  tree2_kernel<<<6, 256, 0, stream>>>(Tb, Ca, Tc, Cb);
  final_kernel<<<1, 256, 0, stream>>>(Tc, Cb, Bband, mug, trans, bt, tags, out);
}